// Round 22
// baseline (2037.929 us; speedup 1.0000x reference)
//
#include <hip/hip_runtime.h>
#include <math.h>

typedef __bf16 bf16_t;
typedef float f32x4 __attribute__((ext_vector_type(4)));
typedef __bf16 bf16x8 __attribute__((ext_vector_type(8)));

union FragU { uint4 u; bf16x8 b; };

#define MFMA_BF16(a, b, c) __builtin_amdgcn_mfma_f32_16x16x32_bf16((a), (b), (c), 0, 0, 0)

__device__ __forceinline__ void glds16(const void* g, void* l) {
  __builtin_amdgcn_global_load_lds((const __attribute__((address_space(1))) void*)g,
                                   (__attribute__((address_space(3))) void*)l, 16, 0, 0);
}

// ------------------------------------------------------------------ rope tables (fp32)
__global__ void rope_k(const int* __restrict__ pos_ids, float* __restrict__ cosb,
                       float* __restrict__ sinb) {
  int s = blockIdx.x;
  int d = threadIdx.x;            // 0..63
  int pair = d >> 5, j = d & 31;
  float p = (float)pos_ids[s * 2 + pair];
  float inv = powf(10000.f, -(float)j / 32.f);
  float v = p * inv;
  float c = cosf(v), sn = sinf(v);
  cosb[s * 128 + d] = c;  cosb[s * 128 + d + 64] = c;
  sinb[s * 128 + d] = sn; sinb[s * 128 + d + 64] = sn;
}

// ------------------------------------------------------------------ rmsnorm fp32 -> bf16
__global__ __launch_bounds__(256) void rmsnorm_bf_k(const float* __restrict__ in,
                                                    const float* __restrict__ w,
                                                    bf16_t* __restrict__ out, int cols) {
  int row = blockIdx.x;
  const float* x = in + (size_t)row * cols;
  float ss = 0.f;
  for (int c = threadIdx.x; c < cols; c += 256) { float v = x[c]; ss = fmaf(v, v, ss); }
#pragma unroll
  for (int o = 32; o; o >>= 1) ss += __shfl_xor(ss, o);
  __shared__ float red[4];
  if ((threadIdx.x & 63) == 0) red[threadIdx.x >> 6] = ss;
  __syncthreads();
  float tot = red[0] + red[1] + red[2] + red[3];
  float rs = rsqrtf(tot / (float)cols + 1e-6f);
  bf16_t* y = out + (size_t)row * cols;
  for (int c = threadIdx.x; c < cols; c += 256) y[c] = (bf16_t)(x[c] * rs * w[c]);
}

// ------------------------------------------------------------------ transpose+convert: in (K,N) f32 -> out (N,Kpad) bf16, zero-pad k>=K
__global__ __launch_bounds__(256) void transpose_cvt_k(const float* __restrict__ in,
                                                       bf16_t* __restrict__ out,
                                                       int K, int N, int Kpad) {
  __shared__ float t[32][33];
  int k0 = blockIdx.x * 32, n0 = blockIdx.y * 32;
  int tx = threadIdx.x & 31, ty = threadIdx.x >> 5;  // 8 rows
#pragma unroll
  for (int i = 0; i < 4; ++i) {
    int k = k0 + ty + 8 * i;
    t[ty + 8 * i][tx] = (k < K) ? in[(size_t)k * N + n0 + tx] : 0.f;
  }
  __syncthreads();
#pragma unroll
  for (int i = 0; i < 4; ++i) {
    int n = n0 + ty + 8 * i;
    out[(size_t)n * Kpad + k0 + tx] = (bf16_t)t[tx][ty + 8 * i];
  }
}

// ------------------------------------------------------------------ transpose+convert for interleaved gate|up weights:
// dst row = (n/32)*64 + grpoff + (n%32)  (grpoff 0 = gate, 32 = up)
__global__ __launch_bounds__(256) void transpose_cvt_gu_k(const float* __restrict__ in,
                                                          bf16_t* __restrict__ out,
                                                          int K, int N, int Kpad, int grpoff) {
  __shared__ float t[32][33];
  int k0 = blockIdx.x * 32, n0 = blockIdx.y * 32;
  int tx = threadIdx.x & 31, ty = threadIdx.x >> 5;
#pragma unroll
  for (int i = 0; i < 4; ++i) {
    int k = k0 + ty + 8 * i;
    t[ty + 8 * i][tx] = (k < K) ? in[(size_t)k * N + n0 + tx] : 0.f;
  }
  __syncthreads();
#pragma unroll
  for (int i = 0; i < 4; ++i) {
    int n = n0 + ty + 8 * i;
    int row = ((n >> 5) << 6) + grpoff + (n & 31);
    out[(size_t)row * Kpad + k0 + tx] = (bf16_t)t[tx][ty + 8 * i];
  }
}

// ------------------------------------------------------------------ straight convert with K-pad: in (R,K) f32 -> out (R,Kpad) bf16
__global__ void convert_pad_k(const float* __restrict__ in, bf16_t* __restrict__ out,
                              int R, int K, int Kpad) {
  int idx = blockIdx.x * 256 + threadIdx.x;
  if (idx < R * Kpad) {
    int r = idx / Kpad, k = idx - r * Kpad;
    out[idx] = (k < K) ? (bf16_t)in[(size_t)r * K + k] : (bf16_t)0.f;
  }
}

// ------------------------------------------------------------------ qk rmsnorm + rope: qkv bf16 -> q_bf (scaled, [h][s][d]), k_bf
__global__ __launch_bounds__(128) void qknorm_rope_k(const bf16_t* __restrict__ qkv,
    const float* __restrict__ qn, const float* __restrict__ kn,
    const float* __restrict__ cosb, const float* __restrict__ sinb,
    bf16_t* __restrict__ qo, bf16_t* __restrict__ ko) {
  const int s = blockIdx.x / 12, h = blockIdx.x % 12;
  const int d = threadIdx.x;  // 0..127
  __shared__ float nrm[128];
  __shared__ float red[2];
  const float cs = cosb[s * 128 + d], sn = sinb[s * 128 + d];
  const float QS = 0.08838834764831845f * 1.4426950408889634f;  // D^-0.5 * log2(e)
#pragma unroll
  for (int part = 0; part < 2; ++part) {
    const bf16_t* p = qkv + (size_t)s * 4608 + part * 1536 + h * 128;
    float v = (float)p[d];
    float ss = v * v;
#pragma unroll
    for (int o = 32; o; o >>= 1) ss += __shfl_xor(ss, o);
    if ((d & 63) == 0) red[d >> 6] = ss;
    __syncthreads();
    float rs = rsqrtf((red[0] + red[1]) * (1.f / 128.f) + 1e-6f);
    float nv = v * rs * (part ? kn[d] : qn[d]);
    nrm[d] = nv;
    __syncthreads();
    float rot = (d < 64) ? -nrm[d + 64] : nrm[d - 64];
    float val = nv * cs + rot * sn;
    bf16_t* dst = part ? ko : qo;
    dst[((size_t)h * 1600 + s) * 128 + d] = (bf16_t)(part ? val : val * QS);
    __syncthreads();
  }
}

// ------------------------------------------------------------------ v transpose: qkv bf16 [s][2C + h*128 + d] -> vt [h][d][s]
__global__ __launch_bounds__(256) void vtrans_k(const bf16_t* __restrict__ qkv,
                                                bf16_t* __restrict__ vt) {
  __shared__ __align__(16) bf16_t t[128][136];
  const int h = blockIdx.x, s0 = blockIdx.y * 128;
  const int tx = threadIdx.x & 15, ty = threadIdx.x >> 4;
#pragma unroll
  for (int i = 0; i < 8; ++i) {
    int sl = ty + 16 * i, s = s0 + sl;
    uint4 v = {0u, 0u, 0u, 0u};
    if (s < 1600) v = *(const uint4*)&qkv[(size_t)s * 4608 + 3072 + h * 128 + tx * 8];
    *(uint4*)&t[sl][tx * 8] = v;
  }
  __syncthreads();
  if (s0 + tx * 8 < 1600) {
#pragma unroll
    for (int i = 0; i < 8; ++i) {
      int dd = ty + 16 * i;
      bf16_t tmp[8];
#pragma unroll
      for (int j = 0; j < 8; ++j) tmp[j] = t[tx * 8 + j][dd];
      *(uint4*)&vt[(size_t)(h * 128 + dd) * 1600 + s0 + tx * 8] = *(uint4*)tmp;
    }
  }
}

// ------------------------------------------------------------------ flash attention, LDS-staged K/V shared by 4 waves (64 q-rows/block),
// 3-buffer counted-vmcnt pipeline. Fixed-max softmax:
// score*log2e <= sqrt(128)*log2e = 16.33 -> p = exp2(s-16), no running max.
__global__ __launch_bounds__(256) void attn_mfma(const bf16_t* __restrict__ qg,
    const bf16_t* __restrict__ kg, const bf16_t* __restrict__ vg,
    bf16_t* __restrict__ o) {
  const int bid = blockIdx.x;                 // grid 300 = 12h * 25 qtiles
  const int xcd = bid & 7, sub = bid >> 3;
  const int swz = (xcd < 4 ? xcd * 38 : 4 * 38 + (xcd - 4) * 37) + sub;
  const int h = swz / 25;
  const int q0 = (swz % 25) * 64;
  const int tid = threadIdx.x;       // 0..255
  const int w = tid >> 6, lane = tid & 63;
  const int fq = lane >> 4, fr = lane & 15;
  const bf16_t* qh = qg + (size_t)h * 1600 * 128;
  const bf16_t* kh = kg + (size_t)h * 1600 * 128;
  const bf16_t* vh = vg + (size_t)h * 128 * 1600;
  __shared__ __align__(16) bf16_t Ks[3][4096];   // [cb16][key32][8]
  __shared__ __align__(16) bf16_t Vs[3][4096];   // [cb4][d128][8]
  __shared__ __align__(16) bf16_t pl[4][512];    // per-wave P [cb4][q16][8]
  int off_k[2], off_v[2], ldsb[2];
#pragma unroll
  for (int c = 0; c < 2; ++c) {
    int j = c * 256 + tid;
    off_k[c] = (j & 31) * 128 + (j >> 5) * 8;
    off_v[c] = (j & 127) * 1600 + (j >> 7) * 8;
    ldsb[c] = (c * 256 + w * 64) * 8;
  }
  FragU aq[4];
#pragma unroll
  for (int db = 0; db < 4; ++db)
    aq[db].u = *(const uint4*)&qh[(size_t)(q0 + w * 16 + fr) * 128 + db * 32 + fq * 8];
  f32x4 zero = {0.f, 0.f, 0.f, 0.f};
  f32x4 oacc[8];
#pragma unroll
  for (int nb = 0; nb < 8; ++nb) oacc[nb] = zero;
  float lrun[4] = {0.f, 0.f, 0.f, 0.f};
#pragma unroll
  for (int c = 0; c < 2; ++c) {
    glds16(kh + off_k[c], &Ks[0][ldsb[c]]);
    glds16(vh + off_v[c], &Vs[0][ldsb[c]]);
  }
#pragma unroll
  for (int c = 0; c < 2; ++c) {
    glds16(kh + 32 * 128 + off_k[c], &Ks[1][ldsb[c]]);
    glds16(vh + 32 + off_v[c], &Vs[1][ldsb[c]]);
  }
  asm volatile("s_waitcnt vmcnt(4)" ::: "memory");
  __builtin_amdgcn_s_barrier();
  int cur = 0;
  for (int t = 0; t < 50; ++t) {
    int stg = cur + 2; if (stg >= 3) stg -= 3;
    if (t + 2 < 50) {
      const int kb = (t + 2) * 32;
#pragma unroll
      for (int c = 0; c < 2; ++c) {
        glds16(kh + (size_t)kb * 128 + off_k[c], &Ks[stg][ldsb[c]]);
        glds16(vh + kb + off_v[c], &Vs[stg][ldsb[c]]);
      }
    }
    f32x4 s0 = zero, s1 = zero;
#pragma unroll
    for (int db = 0; db < 4; ++db) {
      FragU bk0, bk1;
      bk0.u = *(const uint4*)&Ks[cur][((db * 4 + fq) * 32 + fr) * 8];
      bk1.u = *(const uint4*)&Ks[cur][((db * 4 + fq) * 32 + 16 + fr) * 8];
      s0 = MFMA_BF16(aq[db].b, bk0.b, s0);
      s1 = MFMA_BF16(aq[db].b, bk1.b, s1);
    }
    float p0[4], p1[4];
#pragma unroll
    for (int r = 0; r < 4; ++r) {
      p0[r] = exp2f(s0[r] - 16.f);
      p1[r] = exp2f(s1[r] - 16.f);
      lrun[r] += p0[r] + p1[r];
    }
#pragma unroll
    for (int r = 0; r < 4; ++r) {
      int q = fq * 4 + r;
      int kk0 = fr;
      pl[w][((kk0 >> 3) * 16 + q) * 8 + (kk0 & 7)] = (bf16_t)p0[r];
      int kk1 = 16 + fr;
      pl[w][((kk1 >> 3) * 16 + q) * 8 + (kk1 & 7)] = (bf16_t)p1[r];
    }
    FragU ap;
    ap.u = *(const uint4*)&pl[w][(fq * 16 + fr) * 8];
#pragma unroll
    for (int nb = 0; nb < 8; ++nb) {
      FragU bv;
      bv.u = *(const uint4*)&Vs[cur][(fq * 128 + nb * 16 + fr) * 8];
      oacc[nb] = MFMA_BF16(ap.b, bv.b, oacc[nb]);
    }
    if (t + 2 < 50) asm volatile("s_waitcnt vmcnt(4)" ::: "memory");
    else            asm volatile("s_waitcnt vmcnt(0)" ::: "memory");
    __builtin_amdgcn_s_barrier();
    cur = cur + 1; if (cur == 3) cur = 0;
  }
#pragma unroll
  for (int r = 0; r < 4; ++r) {
    lrun[r] += __shfl_xor(lrun[r], 1);
    lrun[r] += __shfl_xor(lrun[r], 2);
    lrun[r] += __shfl_xor(lrun[r], 4);
    lrun[r] += __shfl_xor(lrun[r], 8);
  }
  float inv_[4];
#pragma unroll
  for (int r = 0; r < 4; ++r) inv_[r] = 1.f / lrun[r];
#pragma unroll
  for (int nb = 0; nb < 8; ++nb)
#pragma unroll
    for (int r = 0; r < 4; ++r) {
      int qq = q0 + w * 16 + fq * 4 + r;
      o[(size_t)qq * 1536 + h * 128 + nb * 16 + fr] = (bf16_t)(oacc[nb][r] * inv_[r]);
    }
}

// ------------------------------------------------------------------ gather for conv-as-GEMM (bf16)
__global__ void gather_conv_k(const bf16_t* __restrict__ hf, bf16_t* __restrict__ abuf) {
  int idx = blockIdx.x * 256 + threadIdx.x;  // 400*6144
  if (idx < 400 * 6144) {
    int n = idx / 6144, k = idx - n * 6144;
    abuf[idx] = hf[(size_t)(4 * n + (k & 3)) * 1536 + (k >> 2)];
  }
}

// ------------------------------------------------------------------ 64x64-tile bf16 MFMA GEMM, 3-buffer counted-vmcnt pipeline
template <int ACT, int BIAS, int RES, int OBF>
__global__ __launch_bounds__(256) void gemm64(const bf16_t* __restrict__ A,
    const bf16_t* __restrict__ Bt, const float* __restrict__ bias,
    const float* __restrict__ res, float* __restrict__ outf,
    bf16_t* __restrict__ outb, int M, int N, int K, int lda) {
  __shared__ __align__(16) bf16_t As[3][2048];  // [buf][cb4][row64][8]
  __shared__ __align__(16) bf16_t Bs[3][2048];
  const int tid = threadIdx.x;
  const int lane = tid & 63, w = tid >> 6;
  const int m0 = blockIdx.y * 64, n0 = blockIdx.x * 64;
  const int fq = lane >> 4, fr = lane & 15;
  const int wc = w * 16;
  const bf16_t* ag = A + (size_t)(m0 + lane) * lda + w * 8;
  const bf16_t* bg = Bt + (size_t)(n0 + lane) * K + w * 8;
  f32x4 zero = {0.f, 0.f, 0.f, 0.f};
  f32x4 acc[4];
#pragma unroll
  for (int m = 0; m < 4; ++m) acc[m] = zero;
  const int nt = K >> 5;
  glds16(ag, &As[0][w * 512]); glds16(bg, &Bs[0][w * 512]);
  ag += 32; bg += 32;
  glds16(ag, &As[1][w * 512]); glds16(bg, &Bs[1][w * 512]);
  ag += 32; bg += 32;
  asm volatile("s_waitcnt vmcnt(2)" ::: "memory");
  __builtin_amdgcn_s_barrier();
  int cur = 0;
  for (int t = 0; t < nt; ++t) {
    int stg = cur + 2; if (stg >= 3) stg -= 3;
    if (t + 2 < nt) {
      glds16(ag, &As[stg][w * 512]); glds16(bg, &Bs[stg][w * 512]);
      ag += 32; bg += 32;
    }
    FragU bw, af[4];
    bw.u = *(const uint4*)&Bs[cur][(fq * 64 + wc + fr) * 8];
#pragma unroll
    for (int m = 0; m < 4; ++m)
      af[m].u = *(const uint4*)&As[cur][(fq * 64 + m * 16 + fr) * 8];
#pragma unroll
    for (int m = 0; m < 4; ++m)
      acc[m] = MFMA_BF16(af[m].b, bw.b, acc[m]);
    if (t + 2 < nt) asm volatile("s_waitcnt vmcnt(2)" ::: "memory");
    else            asm volatile("s_waitcnt vmcnt(0)" ::: "memory");
    __builtin_amdgcn_s_barrier();
    cur = cur + 1; if (cur == 3) cur = 0;
  }
#pragma unroll
  for (int m = 0; m < 4; ++m) {
#pragma unroll
    for (int r = 0; r < 4; ++r) {
      int gm = m0 + m * 16 + fq * 4 + r;
      if (gm < M) {
        int gn = n0 + wc + fr;
        float v = acc[m][r];
        if (BIAS) v += bias[gn];
        if (ACT == 1) {
          float x = v;
          float t = 0.7978845608028654f * fmaf(0.044715f * x, x * x, x);
          float e = exp2f(t * 2.8853900817779268f);   // exp(2t)
          v = x * e / (e + 1.f);                       // 0.5x(1+tanh t)
        }
        if (RES) v += res[(size_t)gm * N + gn];
        if (OBF) outb[(size_t)gm * N + gn] = (bf16_t)v;
        else outf[(size_t)gm * N + gn] = v;
      }
    }
  }
}

// ------------------------------------------------------------------ 64x64-tile split-K GEMM: blockIdx.z covers K-chunk; fp32 partials.
template <int KS>
__global__ __launch_bounds__(256) void gemm64sk(const bf16_t* __restrict__ A,
    const bf16_t* __restrict__ Bt, float* __restrict__ part,
    int M, int N, int K, int lda) {
  __shared__ __align__(16) bf16_t As[3][2048];
  __shared__ __align__(16) bf16_t Bs[3][2048];
  const int tid = threadIdx.x;
  const int lane = tid & 63, w = tid >> 6;
  const int m0 = blockIdx.y * 64, n0 = blockIdx.x * 64;
  const int fq = lane >> 4, fr = lane & 15;
  const int wc = w * 16;
  const int kchunk = K / KS;
  const int kbase = blockIdx.z * kchunk;
  const bf16_t* ag = A + (size_t)(m0 + lane) * lda + kbase + w * 8;
  const bf16_t* bg = Bt + (size_t)(n0 + lane) * K + kbase + w * 8;
  f32x4 zero = {0.f, 0.f, 0.f, 0.f};
  f32x4 acc[4];
#pragma unroll
  for (int m = 0; m < 4; ++m) acc[m] = zero;
  const int nt = kchunk >> 5;
  glds16(ag, &As[0][w * 512]); glds16(bg, &Bs[0][w * 512]);
  ag += 32; bg += 32;
  glds16(ag, &As[1][w * 512]); glds16(bg, &Bs[1][w * 512]);
  ag += 32; bg += 32;
  asm volatile("s_waitcnt vmcnt(2)" ::: "memory");
  __builtin_amdgcn_s_barrier();
  int cur = 0;
  for (int t = 0; t < nt; ++t) {
    int stg = cur + 2; if (stg >= 3) stg -= 3;
    if (t + 2 < nt) {
      glds16(ag, &As[stg][w * 512]); glds16(bg, &Bs[stg][w * 512]);
      ag += 32; bg += 32;
    }
    FragU bw, af[4];
    bw.u = *(const uint4*)&Bs[cur][(fq * 64 + wc + fr) * 8];
#pragma unroll
    for (int m = 0; m < 4; ++m)
      af[m].u = *(const uint4*)&As[cur][(fq * 64 + m * 16 + fr) * 8];
#pragma unroll
    for (int m = 0; m < 4; ++m)
      acc[m] = MFMA_BF16(af[m].b, bw.b, acc[m]);
    if (t + 2 < nt) asm volatile("s_waitcnt vmcnt(2)" ::: "memory");
    else            asm volatile("s_waitcnt vmcnt(0)" ::: "memory");
    __builtin_amdgcn_s_barrier();
    cur = cur + 1; if (cur == 3) cur = 0;
  }
  float* ps = part + (size_t)blockIdx.z * M * N;
#pragma unroll
  for (int m = 0; m < 4; ++m) {
#pragma unroll
    for (int r = 0; r < 4; ++r) {
      int gm = m0 + m * 16 + fq * 4 + r;
      if (gm < M) {
        int gn = n0 + wc + fr;
        ps[(size_t)gm * N + gn] = acc[m][r];
      }
    }
  }
}

// ------------------------------------------------------------------ split-K reduce: sum KS slices + bias (+GELU), write bf16 or fp32
template <int KS, int ACT, int OBF>
__global__ void reduce_sk(const float* __restrict__ part, const float* __restrict__ bias,
                          float* __restrict__ outf, bf16_t* __restrict__ outb,
                          int M, int N) {
  int idx = blockIdx.x * 256 + threadIdx.x;
  if (idx < M * N) {
    int n = idx % N;
    float v = 0.f;
#pragma unroll
    for (int s = 0; s < KS; ++s) v += part[(size_t)s * M * N + idx];
    v += bias[n];
    if (ACT == 1) {
      float x = v;
      float t = 0.7978845608028654f * fmaf(0.044715f * x, x * x, x);
      float e = exp2f(t * 2.8853900817779268f);
      v = x * e / (e + 1.f);
    }
    if (OBF) outb[idx] = (bf16_t)v;
    else outf[idx] = v;
  }
}

// ------------------------------------------------------------------ split-K(2) reduce with residual accumulate into h (+optional bias)
template <int BIAS>
__global__ void reduce2_res(const float* __restrict__ part, const float* __restrict__ bias,
                            float* __restrict__ hio, int M, int N) {
  int idx = blockIdx.x * 256 + threadIdx.x;
  if (idx < M * N) {
    float v = part[idx] + part[(size_t)M * N + idx];
    if (BIAS) v += bias[idx % N];
    hio[idx] += v;
  }
}

// ------------------------------------------------------------------ 128x128-tile bf16 MFMA GEMM, 3-buffer counted-vmcnt pipeline (AI=64)
template <int ACT, int BIAS, int RES, int OBF>
__global__ __launch_bounds__(256) void gemm128(const bf16_t* __restrict__ A,
    const bf16_t* __restrict__ Bt, const float* __restrict__ bias,
    const float* __restrict__ res, float* __restrict__ outf,
    bf16_t* __restrict__ outb, int M, int N, int K, int lda) {
  __shared__ __align__(16) bf16_t As[3][4096];  // [buf][cb4][row128][8]
  __shared__ __align__(16) bf16_t Bs[3][4096];
  const int tid = threadIdx.x;
  const int lane = tid & 63, w = tid >> 6;
  const int m0 = blockIdx.y * 128, n0 = blockIdx.x * 128;
  const int wr = (w >> 1) * 64, wc = (w & 1) * 64;
  const int fq = lane >> 4, fr = lane & 15;
  const int u1 = w * 64 + lane, u2 = u1 + 256;
  const int r1 = u1 & 127, c1 = u1 >> 7;
  const int r2 = u2 & 127, c2 = u2 >> 7;
  const bf16_t* a1 = A + (size_t)(m0 + r1) * lda + c1 * 8;
  const bf16_t* a2 = A + (size_t)(m0 + r2) * lda + c2 * 8;
  const bf16_t* b1 = Bt + (size_t)(n0 + r1) * K + c1 * 8;
  const bf16_t* b2 = Bt + (size_t)(n0 + r2) * K + c2 * 8;
  f32x4 zero = {0.f, 0.f, 0.f, 0.f};
  f32x4 acc[4][4];
#pragma unroll
  for (int m = 0; m < 4; ++m)
#pragma unroll
    for (int n = 0; n < 4; ++n) acc[m][n] = zero;
  const int nt = K >> 5;
  glds16(a1, &As[0][w * 512]); glds16(a2, &As[0][2048 + w * 512]);
  glds16(b1, &Bs[0][w * 512]); glds16(b2, &Bs[0][2048 + w * 512]);
  a1 += 32; a2 += 32; b1 += 32; b2 += 32;
  glds16(a1, &As[1][w * 512]); glds16(a2, &As[1][2048 + w * 512]);
  glds16(b1, &Bs[1][w * 512]); glds16(b2, &Bs[1][2048 + w * 512]);
  a1 += 32; a2 += 32; b1 += 32; b2 += 32;
  asm volatile("s_waitcnt vmcnt(4)" ::: "memory");
  __builtin_amdgcn_s_barrier();
  int cur = 0;
  for (int t = 0; t < nt; ++t) {
    int stg = cur + 2; if (stg >= 3) stg -= 3;
    if (t + 2 < nt) {
      glds16(a1, &As[stg][w * 512]); glds16(a2, &As[stg][2048 + w * 512]);
      glds16(b1, &Bs[stg][w * 512]); glds16(b2, &Bs[stg][2048 + w * 512]);
      a1 += 32; a2 += 32; b1 += 32; b2 += 32;
    }
    FragU af[4], bw[4];
#pragma unroll
    for (int m = 0; m < 4; ++m)
      af[m].u = *(const uint4*)&As[cur][(fq * 128 + wr + m * 16 + fr) * 8];
#pragma unroll
    for (int n = 0; n < 4; ++n)
      bw[n].u = *(const uint4*)&Bs[cur][(fq * 128 + wc + n * 16 + fr) * 8];
#pragma unroll
    for (int m = 0; m < 4; ++m)
#pragma unroll
      for (int n = 0; n < 4; ++n)
        acc[m][n] = MFMA_BF16(af[m].b, bw[n].b, acc[m][n]);
    if (t + 2 < nt) asm volatile("s_waitcnt vmcnt(4)" ::: "memory");
    else            asm volatile("s_waitcnt vmcnt(0)" ::: "memory");
    __builtin_amdgcn_s_barrier();
    cur = cur + 1; if (cur == 3) cur = 0;
  }
#pragma unroll
  for (int m = 0; m < 4; ++m) {
#pragma unroll
    for (int r = 0; r < 4; ++r) {
      int gm = m0 + wr + m * 16 + fq * 4 + r;
      if (gm < M) {
#pragma unroll
        for (int n = 0; n < 4; ++n) {
          int gn = n0 + wc + n * 16 + fr;
          float v = acc[m][n][r];
          if (BIAS) v += bias[gn];
          if (ACT == 1) {
            float x = v;
            float t2 = 0.7978845608028654f * fmaf(0.044715f * x, x * x, x);
            float e = exp2f(t2 * 2.8853900817779268f);
            v = x * e / (e + 1.f);
          }
          if (RES) v += res[(size_t)gm * N + gn];
          if (OBF) outb[(size_t)gm * N + gn] = (bf16_t)v;
          else outf[(size_t)gm * N + gn] = v;
        }
      }
    }
  }
}

// ------------------------------------------------------------------ 128x128-tile split-K GEMM: blockIdx.z covers K-chunk; fp32 partials.
template <int KS>
__global__ __launch_bounds__(256) void gemm128sk(const bf16_t* __restrict__ A,
    const bf16_t* __restrict__ Bt, float* __restrict__ part,
    int M, int N, int K, int lda) {
  __shared__ __align__(16) bf16_t As[3][4096];
  __shared__ __align__(16) bf16_t Bs[3][4096];
  const int tid = threadIdx.x;
  const int lane = tid & 63, w = tid >> 6;
  const int m0 = blockIdx.y * 128, n0 = blockIdx.x * 128;
  const int wr = (w >> 1) * 64, wc = (w & 1) * 64;
  const int fq = lane >> 4, fr = lane & 15;
  const int u1 = w * 64 + lane, u2 = u1 + 256;
  const int r1 = u1 & 127, c1 = u1 >> 7;
  const int r2 = u2 & 127, c2 = u2 >> 7;
  const int kchunk = K / KS;
  const int kbase = blockIdx.z * kchunk;
  const bf16_t* a1 = A + (size_t)(m0 + r1) * lda + kbase + c1 * 8;
  const bf16_t* a2 = A + (size_t)(m0 + r2) * lda + kbase + c2 * 8;
  const bf16_t* b1 = Bt + (size_t)(n0 + r1) * K + kbase + c1 * 8;
  const bf16_t* b2 = Bt + (size_t)(n0 + r2) * K + kbase + c2 * 8;
  f32x4 zero = {0.f, 0.f, 0.f, 0.f};
  f32x4 acc[4][4];
#pragma unroll
  for (int m = 0; m < 4; ++m)
#pragma unroll
    for (int n = 0; n < 4; ++n) acc[m][n] = zero;
  const int nt = kchunk >> 5;
  glds16(a1, &As[0][w * 512]); glds16(a2, &As[0][2048 + w * 512]);
  glds16(b1, &Bs[0][w * 512]); glds16(b2, &Bs[0][2048 + w * 512]);
  a1 += 32; a2 += 32; b1 += 32; b2 += 32;
  glds16(a1, &As[1][w * 512]); glds16(a2, &As[1][2048 + w * 512]);
  glds16(b1, &Bs[1][w * 512]); glds16(b2, &Bs[1][2048 + w * 512]);
  a1 += 32; a2 += 32; b1 += 32; b2 += 32;
  asm volatile("s_waitcnt vmcnt(4)" ::: "memory");
  __builtin_amdgcn_s_barrier();
  int cur = 0;
  for (int t = 0; t < nt; ++t) {
    int stg = cur + 2; if (stg >= 3) stg -= 3;
    if (t + 2 < nt) {
      glds16(a1, &As[stg][w * 512]); glds16(a2, &As[stg][2048 + w * 512]);
      glds16(b1, &Bs[stg][w * 512]); glds16(b2, &Bs[stg][2048 + w * 512]);
      a1 += 32; a2 += 32; b1 += 32; b2 += 32;
    }
    FragU af[4], bw[4];
#pragma unroll
    for (int m = 0; m < 4; ++m)
      af[m].u = *(const uint4*)&As[cur][(fq * 128 + wr + m * 16 + fr) * 8];
#pragma unroll
    for (int n = 0; n < 4; ++n)
      bw[n].u = *(const uint4*)&Bs[cur][(fq * 128 + wc + n * 16 + fr) * 8];
#pragma unroll
    for (int m = 0; m < 4; ++m)
#pragma unroll
      for (int n = 0; n < 4; ++n)
        acc[m][n] = MFMA_BF16(af[m].b, bw[n].b, acc[m][n]);
    if (t + 2 < nt) asm volatile("s_waitcnt vmcnt(4)" ::: "memory");
    else            asm volatile("s_waitcnt vmcnt(0)" ::: "memory");
    __builtin_amdgcn_s_barrier();
    cur = cur + 1; if (cur == 3) cur = 0;
  }
  float* ps = part + (size_t)blockIdx.z * M * N;
#pragma unroll
  for (int m = 0; m < 4; ++m) {
#pragma unroll
    for (int r = 0; r < 4; ++r) {
      int gm = m0 + wr + m * 16 + fq * 4 + r;
      if (gm < M) {
#pragma unroll
        for (int n = 0; n < 4; ++n) {
          int gn = n0 + wc + n * 16 + fr;
          ps[(size_t)gm * N + gn] = acc[m][n][r];
        }
      }
    }
  }
}

// ------------------------------------------------------------------ 256x256-tile gate|up GEMM, BK=64, 2-buffer, fused silu(gate)*up.
// Bt interleaved: 64-row groups, first 32 = gate cols [g*32,+32), last 32 =
// up of same cols. Wave n-frags 0,1 = gate, 2,3 = up -> in-register silu.
// LDS layout [cb8][row256][8]; staging chunk f = c*512+tid -> row=f&255,
// cb=f>>8 (lanes linear in LDS; global side per-lane). Output [M][4096] bf16.
__global__ __launch_bounds__(512, 2) void gemm256gu(const bf16_t* __restrict__ A,
    const bf16_t* __restrict__ Bt, bf16_t* __restrict__ outb,
    int M, int K, int lda) {
  __shared__ __align__(16) bf16_t As[2][16384];  // 32KB/buf
  __shared__ __align__(16) bf16_t Bs[2][16384];
  const int tid = threadIdx.x;
  const int lane = tid & 63, w = tid >> 6;
  const int m0 = blockIdx.y * 256, n0 = blockIdx.x * 256;
  const int wr = (w >> 2) * 128, wc = (w & 3) * 64;
  const int fq = lane >> 4, fr = lane & 15;
  const bf16_t* ag[4]; const bf16_t* bg[4]; int lb[4];
#pragma unroll
  for (int c = 0; c < 4; ++c) {
    int f = c * 512 + tid;
    int row = f & 255, cb = f >> 8;
    ag[c] = A + (size_t)(m0 + row) * lda + cb * 8;
    bg[c] = Bt + (size_t)(n0 + row) * K + cb * 8;
    lb[c] = (c * 512 + w * 64) * 8;
  }
  f32x4 zero = {0.f, 0.f, 0.f, 0.f};
  f32x4 acc[8][4];
#pragma unroll
  for (int m = 0; m < 8; ++m)
#pragma unroll
    for (int n = 0; n < 4; ++n) acc[m][n] = zero;
  const int nt = K >> 6;   // BK=64; K=1536 -> 24
  // prologue: stage tile 0 into buf 0 (8 glds per thread)
#pragma unroll
  for (int c = 0; c < 4; ++c) {
    glds16(ag[c], &As[0][lb[c]]);
    glds16(bg[c], &Bs[0][lb[c]]);
  }
  asm volatile("s_waitcnt vmcnt(0)" ::: "memory");
  __builtin_amdgcn_s_barrier();
  for (int t = 0; t < nt; ++t) {
    const int cur = t & 1;
    if (t + 1 < nt) {
      const int ko = (t + 1) * 64;
#pragma unroll
      for (int c = 0; c < 4; ++c) {
        glds16(ag[c] + ko, &As[cur ^ 1][lb[c]]);
        glds16(bg[c] + ko, &Bs[cur ^ 1][lb[c]]);
      }
    }
#pragma unroll
    for (int kk = 0; kk < 2; ++kk) {
      FragU bw[4];
#pragma unroll
      for (int n = 0; n < 4; ++n)
        bw[n].u = *(const uint4*)&Bs[cur][((kk * 4 + fq) * 256 + wc + n * 16 + fr) * 8];
      __builtin_amdgcn_s_setprio(1);
#pragma unroll
      for (int m = 0; m < 8; ++m) {
        FragU af;
        af.u = *(const uint4*)&As[cur][((kk * 4 + fq) * 256 + wr + m * 16 + fr) * 8];
#pragma unroll
        for (int n = 0; n < 4; ++n)
          acc[m][n] = MFMA_BF16(af.b, bw[n].b, acc[m][n]);
      }
      __builtin_amdgcn_s_setprio(0);
    }
    asm volatile("s_waitcnt vmcnt(0)" ::: "memory");
    __builtin_amdgcn_s_barrier();
  }
  // epilogue: j base for this wave = (n0 + wc)/2; n=0,1 gate, n=2,3 up
  const int jb = (n0 + wc) >> 1;
#pragma unroll
  for (int m = 0; m < 8; ++m) {
#pragma unroll
    for (int r = 0; r < 4; ++r) {
      int gm = m0 + wr + m * 16 + fq * 4 + r;
      if (gm < M) {
#pragma unroll
        for (int n = 0; n < 2; ++n) {
          int j = jb + n * 16 + fr;
          float g = acc[m][n][r];
          float u = acc[m][n + 2][r];
          float s = g / (1.f + __expf(-g));
          outb[(size_t)gm * 4096 + j] = (bf16_t)(s * u);
        }
      }
    }
  }
}

// ------------------------------------------------------------------ launch
extern "C" void kernel_launch(void* const* d_in, const int* in_sizes, int n_in,
                              void* d_out, int out_size, void* d_ws, size_t ws_size,
                              hipStream_t stream) {
  (void)in_sizes; (void)n_in; (void)out_size;
  const float* pixel     = (const float*)d_in[0];
  const int*   pos_ids   = (const int*)d_in[1];
  const float* w_patch   = (const float*)d_in[3];
  const float* qkv_w     = (const float*)d_in[4];
  const float* qkv_b     = (const float*)d_in[5];
  const float* q_norm_w  = (const float*)d_in[6];
  const float* k_norm_w  = (const float*)d_in[7];
  const float* proj_w    = (const float*)d_in[8];
  const float* proj_b    = (const float*)d_in[9];
  const float* norm1_w   = (const float*)d_in[10];
  const float* norm2_w   = (const float*)d_in[11];
  const float* gate_w    = (const float*)d_in[12];
  const float* up_w      = (const float*)d_in[13];
  const float* down_w    = (const float*)d_in[14];
  const float* post_ln_w = (const float*)d_in[15];
  const float* conv_w    = (const float*)d_in[16];
  const float* conv_b    = (const float*)d_in[17];
  const float* fc1_w     = (const float*)d_in[18];
  const float* fc1_b     = (const float*)d_in[19];
  const float* fc2_w     = (const float*)d_in[20];
  const float* fc2_b     = (const float*)d_in[21];
  float* out = (float*)d_out;

  char* wsb = (char*)d_ws;
  float*  h     = (float*)(wsb + 0);            // 9,830,400 B
  bf16_t* xo    = (bf16_t*)(wsb + 9830400);     // 4,915,200 B (x / o shared)
  char*   R1    = wsb + 14745600;               // 29,491,200 B multi-use
  bf16_t* qkvb  = (bf16_t*)(R1);
  bf16_t* qb    = (bf16_t*)(R1 + 14745600);
  bf16_t* kb    = (bf16_t*)(R1 + 19660800);
  bf16_t* vb    = (bf16_t*)(R1 + 24576000);
  bf16_t* gub   = (bf16_t*)(R1);                // 13,107,200 B activated gate*up
  bf16_t* pixb  = (bf16_t*)(R1);
  bf16_t* ab    = (bf16_t*)(R1);
  bf16_t* dbuf  = (bf16_t*)(R1 + 4915200);
  bf16_t* ebuf  = (bf16_t*)(R1 + 6144000);
  float*  skp   = (float*)(R1 + 11059200);      // 9,830,400 B split-K partials (head)
  float*  cosb  = (float*)(wsb + 44236800);     // 819,200 B
  float*  sinb  = (float*)(wsb + 45056000);     // 819,200 B
  char*   W     = wsb + 45875200;               // 56,623,104 B (per-layer bf16 weights)
  bf16_t* qkvwT = (bf16_t*)(W);
  bf16_t* projT = (bf16_t*)(W + 14155776);
  bf16_t* gateupT = (bf16_t*)(W + 18874368);    // (8192,1536) interleaved gate|up
  bf16_t* downT = (bf16_t*)(W + 44040192);
  bf16_t* convB = (bf16_t*)(W);
  bf16_t* fc1T  = (bf16_t*)(W + 18874368);
  bf16_t* fc2T  = (bf16_t*)(W + 37748736);
  bf16_t* wpT   = (bf16_t*)(wsb + 102498304);   // 3,637,248 B, ends 106,135,552
  float*  skp2  = (float*)(wsb + 106135552);    // 19,660,800 B split-K(2) partials
  const bool big_ws = ws_size >= (size_t)106135552 + 19660800;

  rope_k<<<1600, 64, 0, stream>>>(pos_ids, cosb, sinb);
  convert_pad_k<<<(1600 * 1184 + 255) / 256, 256, 0, stream>>>(pixel, pixb, 1600, 1176, 1184);
  transpose_cvt_k<<<dim3(37, 48), 256, 0, stream>>>(w_patch, wpT, 1176, 1536, 1184);
  gemm64<0, 0, 0, 0><<<dim3(24, 25), 256, 0, stream>>>(
      pixb, wpT, nullptr, nullptr, h, nullptr, 1600, 1536, 1184, 1184);

  for (int l = 0; l < 4; ++l) {
    const float* qw = qkv_w  + (size_t)l * 1536 * 4608;
    const float* pw = proj_w + (size_t)l * 1536 * 1536;
    const float* gw = gate_w + (size_t)l * 1536 * 4096;
    const float* uw = up_w   + (size_t)l * 1536 * 4096;
    const float* dw = down_w + (size_t)l * 4096 * 1536;
    transpose_cvt_k<<<dim3(48, 144), 256, 0, stream>>>(qw, qkvwT, 1536, 4608, 1536);
    transpose_cvt_k<<<dim3(48, 48),  256, 0, stream>>>(pw, projT, 1536, 1536, 1536);
    transpose_cvt_gu_k<<<dim3(48, 128), 256, 0, stream>>>(gw, gateupT, 1536, 4096, 1536, 0);
    transpose_cvt_gu_k<<<dim3(48, 128), 256, 0, stream>>>(uw, gateupT, 1536, 4096, 1536, 32);
    transpose_cvt_k<<<dim3(128, 48), 256, 0, stream>>>(dw, downT, 4096, 1536, 4096);

    rmsnorm_bf_k<<<1600, 256, 0, stream>>>(h, norm1_w + (size_t)l * 1536, xo, 1536);
    gemm128<0, 1, 0, 1><<<dim3(36, 13), 256, 0, stream>>>(
        xo, qkvwT, qkv_b + (size_t)l * 4608, nullptr, nullptr, qkvb, 1600, 4608, 1536, 1536);
    qknorm_rope_k<<<1600 * 12, 128, 0, stream>>>(
        qkvb, q_norm_w + (size_t)l * 128, k_norm_w + (size_t)l * 128, cosb, sinb, qb, kb);
    vtrans_k<<<dim3(12, 13), 256, 0, stream>>>(qkvb, vb);
    attn_mfma<<<300, 256, 0, stream>>>(qb, kb, vb, xo);
    if (big_ws) {
      gemm128sk<2><<<dim3(12, 13, 2), 256, 0, stream>>>(
          xo, projT, skp2, 1600, 1536, 1536, 1536);
      reduce2_res<1><<<(1600 * 1536 + 255) / 256, 256, 0, stream>>>(
          skp2, proj_b + (size_t)l * 1536, h, 1600, 1536);
    } else {
      gemm64<0, 1, 1, 0><<<dim3(24, 25), 256, 0, stream>>>(
          xo, projT, proj_b + (size_t)l * 1536, h, h, nullptr, 1600, 1536, 1536, 1536);
    }
    rmsnorm_bf_k<<<1600, 256, 0, stream>>>(h, norm2_w + (size_t)l * 1536, xo, 1536);
    gemm256gu<<<dim3(32, 7), 512, 0, stream>>>(
        xo, gateupT, gub, 1600, 1536, 1536);
    if (big_ws) {
      gemm128sk<2><<<dim3(12, 13, 2), 256, 0, stream>>>(
          gub, downT, skp2, 1600, 1536, 4096, 4096);
      reduce2_res<0><<<(1600 * 1536 + 255) / 256, 256, 0, stream>>>(
          skp2, nullptr, h, 1600, 1536);
    } else {
      gemm64<0, 0, 1, 0><<<dim3(24, 25), 256, 0, stream>>>(
          gub, downT, nullptr, h, h, nullptr, 1600, 1536, 4096, 4096);
    }
  }

  // head
  convert_pad_k<<<(1536 * 6144 + 255) / 256, 256, 0, stream>>>(conv_w, convB, 1536, 6144, 6144);
  transpose_cvt_k<<<dim3(48, 192), 256, 0, stream>>>(fc1_w, fc1T, 1536, 6144, 1536);
  transpose_cvt_k<<<dim3(192, 48), 256, 0, stream>>>(fc2_w, fc2T, 6144, 1536, 6144);
  rmsnorm_bf_k<<<1600, 256, 0, stream>>>(h, post_ln_w, xo, 1536);
  gather_conv_k<<<(400 * 6144 + 255) / 256, 256, 0, stream>>>(xo, ab);
  gemm64sk<4><<<dim3(24, 7, 4), 256, 0, stream>>>(ab, convB, skp, 400, 1536, 6144, 6144);
  reduce_sk<4, 0, 1><<<(400 * 1536 + 255) / 256, 256, 0, stream>>>(
      skp, conv_b, nullptr, dbuf, 400, 1536);
  gemm64<1, 1, 0, 1><<<dim3(96, 7), 256, 0, stream>>>(
      dbuf, fc1T, fc1_b, nullptr, nullptr, ebuf, 400, 6144, 1536, 1536);
  gemm64sk<4><<<dim3(24, 7, 4), 256, 0, stream>>>(ebuf, fc2T, skp, 400, 1536, 6144, 6144);
  reduce_sk<4, 0, 0><<<(400 * 1536 + 255) / 256, 256, 0, stream>>>(
      skp, fc2_b, out, nullptr, 400, 1536);
}

// Round 23
// 1989.362 us; speedup vs baseline: 1.0244x; 1.0244x over previous
//
#include <hip/hip_runtime.h>
#include <math.h>

typedef __bf16 bf16_t;
typedef float f32x4 __attribute__((ext_vector_type(4)));
typedef __bf16 bf16x8 __attribute__((ext_vector_type(8)));

union FragU { uint4 u; bf16x8 b; };

#define MFMA_BF16(a, b, c) __builtin_amdgcn_mfma_f32_16x16x32_bf16((a), (b), (c), 0, 0, 0)

__device__ __forceinline__ void glds16(const void* g, void* l) {
  __builtin_amdgcn_global_load_lds((const __attribute__((address_space(1))) void*)g,
                                   (__attribute__((address_space(3))) void*)l, 16, 0, 0);
}

// ------------------------------------------------------------------ rope tables (fp32)
__global__ void rope_k(const int* __restrict__ pos_ids, float* __restrict__ cosb,
                       float* __restrict__ sinb) {
  int s = blockIdx.x;
  int d = threadIdx.x;            // 0..63
  int pair = d >> 5, j = d & 31;
  float p = (float)pos_ids[s * 2 + pair];
  float inv = powf(10000.f, -(float)j / 32.f);
  float v = p * inv;
  float c = cosf(v), sn = sinf(v);
  cosb[s * 128 + d] = c;  cosb[s * 128 + d + 64] = c;
  sinb[s * 128 + d] = sn; sinb[s * 128 + d + 64] = sn;
}

// ------------------------------------------------------------------ rmsnorm fp32 -> bf16
__global__ __launch_bounds__(256) void rmsnorm_bf_k(const float* __restrict__ in,
                                                    const float* __restrict__ w,
                                                    bf16_t* __restrict__ out, int cols) {
  int row = blockIdx.x;
  const float* x = in + (size_t)row * cols;
  float ss = 0.f;
  for (int c = threadIdx.x; c < cols; c += 256) { float v = x[c]; ss = fmaf(v, v, ss); }
#pragma unroll
  for (int o = 32; o; o >>= 1) ss += __shfl_xor(ss, o);
  __shared__ float red[4];
  if ((threadIdx.x & 63) == 0) red[threadIdx.x >> 6] = ss;
  __syncthreads();
  float tot = red[0] + red[1] + red[2] + red[3];
  float rs = rsqrtf(tot / (float)cols + 1e-6f);
  bf16_t* y = out + (size_t)row * cols;
  for (int c = threadIdx.x; c < cols; c += 256) y[c] = (bf16_t)(x[c] * rs * w[c]);
}

// ------------------------------------------------------------------ transpose+convert: in (K,N) f32 -> out (N,Kpad) bf16, zero-pad k>=K
__global__ __launch_bounds__(256) void transpose_cvt_k(const float* __restrict__ in,
                                                       bf16_t* __restrict__ out,
                                                       int K, int N, int Kpad) {
  __shared__ float t[32][33];
  int k0 = blockIdx.x * 32, n0 = blockIdx.y * 32;
  int tx = threadIdx.x & 31, ty = threadIdx.x >> 5;  // 8 rows
#pragma unroll
  for (int i = 0; i < 4; ++i) {
    int k = k0 + ty + 8 * i;
    t[ty + 8 * i][tx] = (k < K) ? in[(size_t)k * N + n0 + tx] : 0.f;
  }
  __syncthreads();
#pragma unroll
  for (int i = 0; i < 4; ++i) {
    int n = n0 + ty + 8 * i;
    out[(size_t)n * Kpad + k0 + tx] = (bf16_t)t[tx][ty + 8 * i];
  }
}

// ------------------------------------------------------------------ transpose+convert for interleaved gate|up weights:
// dst row = (n/32)*64 + grpoff + (n%32)  (grpoff 0 = gate, 32 = up)
__global__ __launch_bounds__(256) void transpose_cvt_gu_k(const float* __restrict__ in,
                                                          bf16_t* __restrict__ out,
                                                          int K, int N, int Kpad, int grpoff) {
  __shared__ float t[32][33];
  int k0 = blockIdx.x * 32, n0 = blockIdx.y * 32;
  int tx = threadIdx.x & 31, ty = threadIdx.x >> 5;
#pragma unroll
  for (int i = 0; i < 4; ++i) {
    int k = k0 + ty + 8 * i;
    t[ty + 8 * i][tx] = (k < K) ? in[(size_t)k * N + n0 + tx] : 0.f;
  }
  __syncthreads();
#pragma unroll
  for (int i = 0; i < 4; ++i) {
    int n = n0 + ty + 8 * i;
    int row = ((n >> 5) << 6) + grpoff + (n & 31);
    out[(size_t)row * Kpad + k0 + tx] = (bf16_t)t[tx][ty + 8 * i];
  }
}

// ------------------------------------------------------------------ straight convert with K-pad: in (R,K) f32 -> out (R,Kpad) bf16
__global__ void convert_pad_k(const float* __restrict__ in, bf16_t* __restrict__ out,
                              int R, int K, int Kpad) {
  int idx = blockIdx.x * 256 + threadIdx.x;
  if (idx < R * Kpad) {
    int r = idx / Kpad, k = idx - r * Kpad;
    out[idx] = (k < K) ? (bf16_t)in[(size_t)r * K + k] : (bf16_t)0.f;
  }
}

// ------------------------------------------------------------------ qk rmsnorm + rope: qkv bf16 -> q_bf (scaled, [h][s][d]), k_bf
__global__ __launch_bounds__(128) void qknorm_rope_k(const bf16_t* __restrict__ qkv,
    const float* __restrict__ qn, const float* __restrict__ kn,
    const float* __restrict__ cosb, const float* __restrict__ sinb,
    bf16_t* __restrict__ qo, bf16_t* __restrict__ ko) {
  const int s = blockIdx.x / 12, h = blockIdx.x % 12;
  const int d = threadIdx.x;  // 0..127
  __shared__ float nrm[128];
  __shared__ float red[2];
  const float cs = cosb[s * 128 + d], sn = sinb[s * 128 + d];
  const float QS = 0.08838834764831845f * 1.4426950408889634f;  // D^-0.5 * log2(e)
#pragma unroll
  for (int part = 0; part < 2; ++part) {
    const bf16_t* p = qkv + (size_t)s * 4608 + part * 1536 + h * 128;
    float v = (float)p[d];
    float ss = v * v;
#pragma unroll
    for (int o = 32; o; o >>= 1) ss += __shfl_xor(ss, o);
    if ((d & 63) == 0) red[d >> 6] = ss;
    __syncthreads();
    float rs = rsqrtf((red[0] + red[1]) * (1.f / 128.f) + 1e-6f);
    float nv = v * rs * (part ? kn[d] : qn[d]);
    nrm[d] = nv;
    __syncthreads();
    float rot = (d < 64) ? -nrm[d + 64] : nrm[d - 64];
    float val = nv * cs + rot * sn;
    bf16_t* dst = part ? ko : qo;
    dst[((size_t)h * 1600 + s) * 128 + d] = (bf16_t)(part ? val : val * QS);
    __syncthreads();
  }
}

// ------------------------------------------------------------------ v transpose: qkv bf16 [s][2C + h*128 + d] -> vt [h][d][s]
__global__ __launch_bounds__(256) void vtrans_k(const bf16_t* __restrict__ qkv,
                                                bf16_t* __restrict__ vt) {
  __shared__ __align__(16) bf16_t t[128][136];
  const int h = blockIdx.x, s0 = blockIdx.y * 128;
  const int tx = threadIdx.x & 15, ty = threadIdx.x >> 4;
#pragma unroll
  for (int i = 0; i < 8; ++i) {
    int sl = ty + 16 * i, s = s0 + sl;
    uint4 v = {0u, 0u, 0u, 0u};
    if (s < 1600) v = *(const uint4*)&qkv[(size_t)s * 4608 + 3072 + h * 128 + tx * 8];
    *(uint4*)&t[sl][tx * 8] = v;
  }
  __syncthreads();
  if (s0 + tx * 8 < 1600) {
#pragma unroll
    for (int i = 0; i < 8; ++i) {
      int dd = ty + 16 * i;
      bf16_t tmp[8];
#pragma unroll
      for (int j = 0; j < 8; ++j) tmp[j] = t[tx * 8 + j][dd];
      *(uint4*)&vt[(size_t)(h * 128 + dd) * 1600 + s0 + tx * 8] = *(uint4*)tmp;
    }
  }
}

// ------------------------------------------------------------------ flash attention, LDS-staged K/V shared by 4 waves (64 q-rows/block),
// 3-buffer counted-vmcnt pipeline. Fixed-max softmax:
// score*log2e <= sqrt(128)*log2e = 16.33 -> p = exp2(s-16), no running max.
__global__ __launch_bounds__(256) void attn_mfma(const bf16_t* __restrict__ qg,
    const bf16_t* __restrict__ kg, const bf16_t* __restrict__ vg,
    bf16_t* __restrict__ o) {
  const int bid = blockIdx.x;                 // grid 300 = 12h * 25 qtiles
  const int xcd = bid & 7, sub = bid >> 3;
  const int swz = (xcd < 4 ? xcd * 38 : 4 * 38 + (xcd - 4) * 37) + sub;
  const int h = swz / 25;
  const int q0 = (swz % 25) * 64;
  const int tid = threadIdx.x;       // 0..255
  const int w = tid >> 6, lane = tid & 63;
  const int fq = lane >> 4, fr = lane & 15;
  const bf16_t* qh = qg + (size_t)h * 1600 * 128;
  const bf16_t* kh = kg + (size_t)h * 1600 * 128;
  const bf16_t* vh = vg + (size_t)h * 128 * 1600;
  __shared__ __align__(16) bf16_t Ks[3][4096];   // [cb16][key32][8]
  __shared__ __align__(16) bf16_t Vs[3][4096];   // [cb4][d128][8]
  __shared__ __align__(16) bf16_t pl[4][512];    // per-wave P [cb4][q16][8]
  int off_k[2], off_v[2], ldsb[2];
#pragma unroll
  for (int c = 0; c < 2; ++c) {
    int j = c * 256 + tid;
    off_k[c] = (j & 31) * 128 + (j >> 5) * 8;
    off_v[c] = (j & 127) * 1600 + (j >> 7) * 8;
    ldsb[c] = (c * 256 + w * 64) * 8;
  }
  FragU aq[4];
#pragma unroll
  for (int db = 0; db < 4; ++db)
    aq[db].u = *(const uint4*)&qh[(size_t)(q0 + w * 16 + fr) * 128 + db * 32 + fq * 8];
  f32x4 zero = {0.f, 0.f, 0.f, 0.f};
  f32x4 oacc[8];
#pragma unroll
  for (int nb = 0; nb < 8; ++nb) oacc[nb] = zero;
  float lrun[4] = {0.f, 0.f, 0.f, 0.f};
#pragma unroll
  for (int c = 0; c < 2; ++c) {
    glds16(kh + off_k[c], &Ks[0][ldsb[c]]);
    glds16(vh + off_v[c], &Vs[0][ldsb[c]]);
  }
#pragma unroll
  for (int c = 0; c < 2; ++c) {
    glds16(kh + 32 * 128 + off_k[c], &Ks[1][ldsb[c]]);
    glds16(vh + 32 + off_v[c], &Vs[1][ldsb[c]]);
  }
  asm volatile("s_waitcnt vmcnt(4)" ::: "memory");
  __builtin_amdgcn_s_barrier();
  int cur = 0;
  for (int t = 0; t < 50; ++t) {
    int stg = cur + 2; if (stg >= 3) stg -= 3;
    if (t + 2 < 50) {
      const int kb = (t + 2) * 32;
#pragma unroll
      for (int c = 0; c < 2; ++c) {
        glds16(kh + (size_t)kb * 128 + off_k[c], &Ks[stg][ldsb[c]]);
        glds16(vh + kb + off_v[c], &Vs[stg][ldsb[c]]);
      }
    }
    f32x4 s0 = zero, s1 = zero;
#pragma unroll
    for (int db = 0; db < 4; ++db) {
      FragU bk0, bk1;
      bk0.u = *(const uint4*)&Ks[cur][((db * 4 + fq) * 32 + fr) * 8];
      bk1.u = *(const uint4*)&Ks[cur][((db * 4 + fq) * 32 + 16 + fr) * 8];
      s0 = MFMA_BF16(aq[db].b, bk0.b, s0);
      s1 = MFMA_BF16(aq[db].b, bk1.b, s1);
    }
    float p0[4], p1[4];
#pragma unroll
    for (int r = 0; r < 4; ++r) {
      p0[r] = exp2f(s0[r] - 16.f);
      p1[r] = exp2f(s1[r] - 16.f);
      lrun[r] += p0[r] + p1[r];
    }
#pragma unroll
    for (int r = 0; r < 4; ++r) {
      int q = fq * 4 + r;
      int kk0 = fr;
      pl[w][((kk0 >> 3) * 16 + q) * 8 + (kk0 & 7)] = (bf16_t)p0[r];
      int kk1 = 16 + fr;
      pl[w][((kk1 >> 3) * 16 + q) * 8 + (kk1 & 7)] = (bf16_t)p1[r];
    }
    FragU ap;
    ap.u = *(const uint4*)&pl[w][(fq * 16 + fr) * 8];
#pragma unroll
    for (int nb = 0; nb < 8; ++nb) {
      FragU bv;
      bv.u = *(const uint4*)&Vs[cur][(fq * 128 + nb * 16 + fr) * 8];
      oacc[nb] = MFMA_BF16(ap.b, bv.b, oacc[nb]);
    }
    if (t + 2 < 50) asm volatile("s_waitcnt vmcnt(4)" ::: "memory");
    else            asm volatile("s_waitcnt vmcnt(0)" ::: "memory");
    __builtin_amdgcn_s_barrier();
    cur = cur + 1; if (cur == 3) cur = 0;
  }
#pragma unroll
  for (int r = 0; r < 4; ++r) {
    lrun[r] += __shfl_xor(lrun[r], 1);
    lrun[r] += __shfl_xor(lrun[r], 2);
    lrun[r] += __shfl_xor(lrun[r], 4);
    lrun[r] += __shfl_xor(lrun[r], 8);
  }
  float inv_[4];
#pragma unroll
  for (int r = 0; r < 4; ++r) inv_[r] = 1.f / lrun[r];
#pragma unroll
  for (int nb = 0; nb < 8; ++nb)
#pragma unroll
    for (int r = 0; r < 4; ++r) {
      int qq = q0 + w * 16 + fq * 4 + r;
      o[(size_t)qq * 1536 + h * 128 + nb * 16 + fr] = (bf16_t)(oacc[nb][r] * inv_[r]);
    }
}

// ------------------------------------------------------------------ gather for conv-as-GEMM (bf16)
__global__ void gather_conv_k(const bf16_t* __restrict__ hf, bf16_t* __restrict__ abuf) {
  int idx = blockIdx.x * 256 + threadIdx.x;  // 400*6144
  if (idx < 400 * 6144) {
    int n = idx / 6144, k = idx - n * 6144;
    abuf[idx] = hf[(size_t)(4 * n + (k & 3)) * 1536 + (k >> 2)];
  }
}

// ------------------------------------------------------------------ 64x64-tile bf16 MFMA GEMM, 3-buffer counted-vmcnt pipeline
template <int ACT, int BIAS, int RES, int OBF>
__global__ __launch_bounds__(256) void gemm64(const bf16_t* __restrict__ A,
    const bf16_t* __restrict__ Bt, const float* __restrict__ bias,
    const float* __restrict__ res, float* __restrict__ outf,
    bf16_t* __restrict__ outb, int M, int N, int K, int lda) {
  __shared__ __align__(16) bf16_t As[3][2048];  // [buf][cb4][row64][8]
  __shared__ __align__(16) bf16_t Bs[3][2048];
  const int tid = threadIdx.x;
  const int lane = tid & 63, w = tid >> 6;
  const int m0 = blockIdx.y * 64, n0 = blockIdx.x * 64;
  const int fq = lane >> 4, fr = lane & 15;
  const int wc = w * 16;
  const bf16_t* ag = A + (size_t)(m0 + lane) * lda + w * 8;
  const bf16_t* bg = Bt + (size_t)(n0 + lane) * K + w * 8;
  f32x4 zero = {0.f, 0.f, 0.f, 0.f};
  f32x4 acc[4];
#pragma unroll
  for (int m = 0; m < 4; ++m) acc[m] = zero;
  const int nt = K >> 5;
  glds16(ag, &As[0][w * 512]); glds16(bg, &Bs[0][w * 512]);
  ag += 32; bg += 32;
  glds16(ag, &As[1][w * 512]); glds16(bg, &Bs[1][w * 512]);
  ag += 32; bg += 32;
  asm volatile("s_waitcnt vmcnt(2)" ::: "memory");
  __builtin_amdgcn_s_barrier();
  int cur = 0;
  for (int t = 0; t < nt; ++t) {
    int stg = cur + 2; if (stg >= 3) stg -= 3;
    if (t + 2 < nt) {
      glds16(ag, &As[stg][w * 512]); glds16(bg, &Bs[stg][w * 512]);
      ag += 32; bg += 32;
    }
    FragU bw, af[4];
    bw.u = *(const uint4*)&Bs[cur][(fq * 64 + wc + fr) * 8];
#pragma unroll
    for (int m = 0; m < 4; ++m)
      af[m].u = *(const uint4*)&As[cur][(fq * 64 + m * 16 + fr) * 8];
#pragma unroll
    for (int m = 0; m < 4; ++m)
      acc[m] = MFMA_BF16(af[m].b, bw.b, acc[m]);
    if (t + 2 < nt) asm volatile("s_waitcnt vmcnt(2)" ::: "memory");
    else            asm volatile("s_waitcnt vmcnt(0)" ::: "memory");
    __builtin_amdgcn_s_barrier();
    cur = cur + 1; if (cur == 3) cur = 0;
  }
#pragma unroll
  for (int m = 0; m < 4; ++m) {
#pragma unroll
    for (int r = 0; r < 4; ++r) {
      int gm = m0 + m * 16 + fq * 4 + r;
      if (gm < M) {
        int gn = n0 + wc + fr;
        float v = acc[m][r];
        if (BIAS) v += bias[gn];
        if (ACT == 1) {
          float x = v;
          float t = 0.7978845608028654f * fmaf(0.044715f * x, x * x, x);
          float e = exp2f(t * 2.8853900817779268f);   // exp(2t)
          v = x * e / (e + 1.f);                       // 0.5x(1+tanh t)
        }
        if (RES) v += res[(size_t)gm * N + gn];
        if (OBF) outb[(size_t)gm * N + gn] = (bf16_t)v;
        else outf[(size_t)gm * N + gn] = v;
      }
    }
  }
}

// ------------------------------------------------------------------ 64x64-tile split-K GEMM: blockIdx.z covers K-chunk; fp32 partials.
template <int KS>
__global__ __launch_bounds__(256) void gemm64sk(const bf16_t* __restrict__ A,
    const bf16_t* __restrict__ Bt, float* __restrict__ part,
    int M, int N, int K, int lda) {
  __shared__ __align__(16) bf16_t As[3][2048];
  __shared__ __align__(16) bf16_t Bs[3][2048];
  const int tid = threadIdx.x;
  const int lane = tid & 63, w = tid >> 6;
  const int m0 = blockIdx.y * 64, n0 = blockIdx.x * 64;
  const int fq = lane >> 4, fr = lane & 15;
  const int wc = w * 16;
  const int kchunk = K / KS;
  const int kbase = blockIdx.z * kchunk;
  const bf16_t* ag = A + (size_t)(m0 + lane) * lda + kbase + w * 8;
  const bf16_t* bg = Bt + (size_t)(n0 + lane) * K + kbase + w * 8;
  f32x4 zero = {0.f, 0.f, 0.f, 0.f};
  f32x4 acc[4];
#pragma unroll
  for (int m = 0; m < 4; ++m) acc[m] = zero;
  const int nt = kchunk >> 5;
  glds16(ag, &As[0][w * 512]); glds16(bg, &Bs[0][w * 512]);
  ag += 32; bg += 32;
  glds16(ag, &As[1][w * 512]); glds16(bg, &Bs[1][w * 512]);
  ag += 32; bg += 32;
  asm volatile("s_waitcnt vmcnt(2)" ::: "memory");
  __builtin_amdgcn_s_barrier();
  int cur = 0;
  for (int t = 0; t < nt; ++t) {
    int stg = cur + 2; if (stg >= 3) stg -= 3;
    if (t + 2 < nt) {
      glds16(ag, &As[stg][w * 512]); glds16(bg, &Bs[stg][w * 512]);
      ag += 32; bg += 32;
    }
    FragU bw, af[4];
    bw.u = *(const uint4*)&Bs[cur][(fq * 64 + wc + fr) * 8];
#pragma unroll
    for (int m = 0; m < 4; ++m)
      af[m].u = *(const uint4*)&As[cur][(fq * 64 + m * 16 + fr) * 8];
#pragma unroll
    for (int m = 0; m < 4; ++m)
      acc[m] = MFMA_BF16(af[m].b, bw.b, acc[m]);
    if (t + 2 < nt) asm volatile("s_waitcnt vmcnt(2)" ::: "memory");
    else            asm volatile("s_waitcnt vmcnt(0)" ::: "memory");
    __builtin_amdgcn_s_barrier();
    cur = cur + 1; if (cur == 3) cur = 0;
  }
  float* ps = part + (size_t)blockIdx.z * M * N;
#pragma unroll
  for (int m = 0; m < 4; ++m) {
#pragma unroll
    for (int r = 0; r < 4; ++r) {
      int gm = m0 + m * 16 + fq * 4 + r;
      if (gm < M) {
        int gn = n0 + wc + fr;
        ps[(size_t)gm * N + gn] = acc[m][r];
      }
    }
  }
}

// ------------------------------------------------------------------ split-K reduce: sum KS slices + bias (+GELU), write bf16 or fp32
template <int KS, int ACT, int OBF>
__global__ void reduce_sk(const float* __restrict__ part, const float* __restrict__ bias,
                          float* __restrict__ outf, bf16_t* __restrict__ outb,
                          int M, int N) {
  int idx = blockIdx.x * 256 + threadIdx.x;
  if (idx < M * N) {
    int n = idx % N;
    float v = 0.f;
#pragma unroll
    for (int s = 0; s < KS; ++s) v += part[(size_t)s * M * N + idx];
    v += bias[n];
    if (ACT == 1) {
      float x = v;
      float t = 0.7978845608028654f * fmaf(0.044715f * x, x * x, x);
      float e = exp2f(t * 2.8853900817779268f);
      v = x * e / (e + 1.f);
    }
    if (OBF) outb[idx] = (bf16_t)v;
    else outf[idx] = v;
  }
}

// ------------------------------------------------------------------ split-K(2) reduce with residual accumulate into h (+optional bias)
template <int BIAS>
__global__ void reduce2_res(const float* __restrict__ part, const float* __restrict__ bias,
                            float* __restrict__ hio, int M, int N) {
  int idx = blockIdx.x * 256 + threadIdx.x;
  if (idx < M * N) {
    float v = part[idx] + part[(size_t)M * N + idx];
    if (BIAS) v += bias[idx % N];
    hio[idx] += v;
  }
}

// ------------------------------------------------------------------ 128x128-tile bf16 MFMA GEMM, 3-buffer counted-vmcnt pipeline (AI=64)
template <int ACT, int BIAS, int RES, int OBF>
__global__ __launch_bounds__(256) void gemm128(const bf16_t* __restrict__ A,
    const bf16_t* __restrict__ Bt, const float* __restrict__ bias,
    const float* __restrict__ res, float* __restrict__ outf,
    bf16_t* __restrict__ outb, int M, int N, int K, int lda) {
  __shared__ __align__(16) bf16_t As[3][4096];  // [buf][cb4][row128][8]
  __shared__ __align__(16) bf16_t Bs[3][4096];
  const int tid = threadIdx.x;
  const int lane = tid & 63, w = tid >> 6;
  const int m0 = blockIdx.y * 128, n0 = blockIdx.x * 128;
  const int wr = (w >> 1) * 64, wc = (w & 1) * 64;
  const int fq = lane >> 4, fr = lane & 15;
  const int u1 = w * 64 + lane, u2 = u1 + 256;
  const int r1 = u1 & 127, c1 = u1 >> 7;
  const int r2 = u2 & 127, c2 = u2 >> 7;
  const bf16_t* a1 = A + (size_t)(m0 + r1) * lda + c1 * 8;
  const bf16_t* a2 = A + (size_t)(m0 + r2) * lda + c2 * 8;
  const bf16_t* b1 = Bt + (size_t)(n0 + r1) * K + c1 * 8;
  const bf16_t* b2 = Bt + (size_t)(n0 + r2) * K + c2 * 8;
  f32x4 zero = {0.f, 0.f, 0.f, 0.f};
  f32x4 acc[4][4];
#pragma unroll
  for (int m = 0; m < 4; ++m)
#pragma unroll
    for (int n = 0; n < 4; ++n) acc[m][n] = zero;
  const int nt = K >> 5;
  glds16(a1, &As[0][w * 512]); glds16(a2, &As[0][2048 + w * 512]);
  glds16(b1, &Bs[0][w * 512]); glds16(b2, &Bs[0][2048 + w * 512]);
  a1 += 32; a2 += 32; b1 += 32; b2 += 32;
  glds16(a1, &As[1][w * 512]); glds16(a2, &As[1][2048 + w * 512]);
  glds16(b1, &Bs[1][w * 512]); glds16(b2, &Bs[1][2048 + w * 512]);
  a1 += 32; a2 += 32; b1 += 32; b2 += 32;
  asm volatile("s_waitcnt vmcnt(4)" ::: "memory");
  __builtin_amdgcn_s_barrier();
  int cur = 0;
  for (int t = 0; t < nt; ++t) {
    int stg = cur + 2; if (stg >= 3) stg -= 3;
    if (t + 2 < nt) {
      glds16(a1, &As[stg][w * 512]); glds16(a2, &As[stg][2048 + w * 512]);
      glds16(b1, &Bs[stg][w * 512]); glds16(b2, &Bs[stg][2048 + w * 512]);
      a1 += 32; a2 += 32; b1 += 32; b2 += 32;
    }
    FragU af[4], bw[4];
#pragma unroll
    for (int m = 0; m < 4; ++m)
      af[m].u = *(const uint4*)&As[cur][(fq * 128 + wr + m * 16 + fr) * 8];
#pragma unroll
    for (int n = 0; n < 4; ++n)
      bw[n].u = *(const uint4*)&Bs[cur][(fq * 128 + wc + n * 16 + fr) * 8];
#pragma unroll
    for (int m = 0; m < 4; ++m)
#pragma unroll
      for (int n = 0; n < 4; ++n)
        acc[m][n] = MFMA_BF16(af[m].b, bw[n].b, acc[m][n]);
    if (t + 2 < nt) asm volatile("s_waitcnt vmcnt(4)" ::: "memory");
    else            asm volatile("s_waitcnt vmcnt(0)" ::: "memory");
    __builtin_amdgcn_s_barrier();
    cur = cur + 1; if (cur == 3) cur = 0;
  }
#pragma unroll
  for (int m = 0; m < 4; ++m) {
#pragma unroll
    for (int r = 0; r < 4; ++r) {
      int gm = m0 + wr + m * 16 + fq * 4 + r;
      if (gm < M) {
#pragma unroll
        for (int n = 0; n < 4; ++n) {
          int gn = n0 + wc + n * 16 + fr;
          float v = acc[m][n][r];
          if (BIAS) v += bias[gn];
          if (ACT == 1) {
            float x = v;
            float t2 = 0.7978845608028654f * fmaf(0.044715f * x, x * x, x);
            float e = exp2f(t2 * 2.8853900817779268f);
            v = x * e / (e + 1.f);
          }
          if (RES) v += res[(size_t)gm * N + gn];
          if (OBF) outb[(size_t)gm * N + gn] = (bf16_t)v;
          else outf[(size_t)gm * N + gn] = v;
        }
      }
    }
  }
}

// ------------------------------------------------------------------ 128x128-tile split-K GEMM: blockIdx.z covers K-chunk; fp32 partials.
template <int KS>
__global__ __launch_bounds__(256) void gemm128sk(const bf16_t* __restrict__ A,
    const bf16_t* __restrict__ Bt, float* __restrict__ part,
    int M, int N, int K, int lda) {
  __shared__ __align__(16) bf16_t As[3][4096];
  __shared__ __align__(16) bf16_t Bs[3][4096];
  const int tid = threadIdx.x;
  const int lane = tid & 63, w = tid >> 6;
  const int m0 = blockIdx.y * 128, n0 = blockIdx.x * 128;
  const int wr = (w >> 1) * 64, wc = (w & 1) * 64;
  const int fq = lane >> 4, fr = lane & 15;
  const int u1 = w * 64 + lane, u2 = u1 + 256;
  const int r1 = u1 & 127, c1 = u1 >> 7;
  const int r2 = u2 & 127, c2 = u2 >> 7;
  const int kchunk = K / KS;
  const int kbase = blockIdx.z * kchunk;
  const bf16_t* a1 = A + (size_t)(m0 + r1) * lda + kbase + c1 * 8;
  const bf16_t* a2 = A + (size_t)(m0 + r2) * lda + kbase + c2 * 8;
  const bf16_t* b1 = Bt + (size_t)(n0 + r1) * K + kbase + c1 * 8;
  const bf16_t* b2 = Bt + (size_t)(n0 + r2) * K + kbase + c2 * 8;
  f32x4 zero = {0.f, 0.f, 0.f, 0.f};
  f32x4 acc[4][4];
#pragma unroll
  for (int m = 0; m < 4; ++m)
#pragma unroll
    for (int n = 0; n < 4; ++n) acc[m][n] = zero;
  const int nt = kchunk >> 5;
  glds16(a1, &As[0][w * 512]); glds16(a2, &As[0][2048 + w * 512]);
  glds16(b1, &Bs[0][w * 512]); glds16(b2, &Bs[0][2048 + w * 512]);
  a1 += 32; a2 += 32; b1 += 32; b2 += 32;
  glds16(a1, &As[1][w * 512]); glds16(a2, &As[1][2048 + w * 512]);
  glds16(b1, &Bs[1][w * 512]); glds16(b2, &Bs[1][2048 + w * 512]);
  a1 += 32; a2 += 32; b1 += 32; b2 += 32;
  asm volatile("s_waitcnt vmcnt(4)" ::: "memory");
  __builtin_amdgcn_s_barrier();
  int cur = 0;
  for (int t = 0; t < nt; ++t) {
    int stg = cur + 2; if (stg >= 3) stg -= 3;
    if (t + 2 < nt) {
      glds16(a1, &As[stg][w * 512]); glds16(a2, &As[stg][2048 + w * 512]);
      glds16(b1, &Bs[stg][w * 512]); glds16(b2, &Bs[stg][2048 + w * 512]);
      a1 += 32; a2 += 32; b1 += 32; b2 += 32;
    }
    FragU af[4], bw[4];
#pragma unroll
    for (int m = 0; m < 4; ++m)
      af[m].u = *(const uint4*)&As[cur][(fq * 128 + wr + m * 16 + fr) * 8];
#pragma unroll
    for (int n = 0; n < 4; ++n)
      bw[n].u = *(const uint4*)&Bs[cur][(fq * 128 + wc + n * 16 + fr) * 8];
#pragma unroll
    for (int m = 0; m < 4; ++m)
#pragma unroll
      for (int n = 0; n < 4; ++n)
        acc[m][n] = MFMA_BF16(af[m].b, bw[n].b, acc[m][n]);
    if (t + 2 < nt) asm volatile("s_waitcnt vmcnt(4)" ::: "memory");
    else            asm volatile("s_waitcnt vmcnt(0)" ::: "memory");
    __builtin_amdgcn_s_barrier();
    cur = cur + 1; if (cur == 3) cur = 0;
  }
  float* ps = part + (size_t)blockIdx.z * M * N;
#pragma unroll
  for (int m = 0; m < 4; ++m) {
#pragma unroll
    for (int r = 0; r < 4; ++r) {
      int gm = m0 + wr + m * 16 + fq * 4 + r;
      if (gm < M) {
#pragma unroll
        for (int n = 0; n < 4; ++n) {
          int gn = n0 + wc + n * 16 + fr;
          ps[(size_t)gm * N + gn] = acc[m][n][r];
        }
      }
    }
  }
}

// ------------------------------------------------------------------ 256x256-tile gate|up GEMM, 8 waves, 3-buffer counted-vmcnt,
// fused silu(gate)*up epilogue. Bt interleaved: 64-row groups, first 32 =
// gate cols [g*32,+32), last 32 = up of same cols. Wave n-frags 0,1 = gate,
// 2,3 = up -> in-register silu. Output [M][4096] bf16.
__global__ __launch_bounds__(512, 2) void gemm256gu(const bf16_t* __restrict__ A,
    const bf16_t* __restrict__ Bt, bf16_t* __restrict__ outb,
    int M, int K, int lda) {
  __shared__ __align__(16) bf16_t As[3][8192];
  __shared__ __align__(16) bf16_t Bs[3][8192];
  const int tid = threadIdx.x;
  const int lane = tid & 63, w = tid >> 6;
  const int m0 = blockIdx.y * 256, n0 = blockIdx.x * 256;
  const int wr = (w >> 2) * 128, wc = (w & 3) * 64;
  const int fq = lane >> 4, fr = lane & 15;
  const int f0 = tid, f1 = 512 + tid;
  const int r0 = f0 & 255, c0 = f0 >> 8;
  const int r1 = f1 & 255, c1 = f1 >> 8;
  const bf16_t* a0 = A + (size_t)(m0 + r0) * lda + c0 * 8;
  const bf16_t* a1 = A + (size_t)(m0 + r1) * lda + c1 * 8;
  const bf16_t* b0 = Bt + (size_t)(n0 + r0) * K + c0 * 8;
  const bf16_t* b1 = Bt + (size_t)(n0 + r1) * K + c1 * 8;
  const int l0 = (w * 64) * 8;
  const int l1 = (512 + w * 64) * 8;
  f32x4 zero = {0.f, 0.f, 0.f, 0.f};
  f32x4 acc[8][4];
#pragma unroll
  for (int m = 0; m < 8; ++m)
#pragma unroll
    for (int n = 0; n < 4; ++n) acc[m][n] = zero;
  const int nt = K >> 5;
  glds16(a0, &As[0][l0]); glds16(a1, &As[0][l1]);
  glds16(b0, &Bs[0][l0]); glds16(b1, &Bs[0][l1]);
  a0 += 32; a1 += 32; b0 += 32; b1 += 32;
  glds16(a0, &As[1][l0]); glds16(a1, &As[1][l1]);
  glds16(b0, &Bs[1][l0]); glds16(b1, &Bs[1][l1]);
  a0 += 32; a1 += 32; b0 += 32; b1 += 32;
  asm volatile("s_waitcnt vmcnt(4)" ::: "memory");
  __builtin_amdgcn_s_barrier();
  int cur = 0;
  for (int t = 0; t < nt; ++t) {
    int stg = cur + 2; if (stg >= 3) stg -= 3;
    if (t + 2 < nt) {
      glds16(a0, &As[stg][l0]); glds16(a1, &As[stg][l1]);
      glds16(b0, &Bs[stg][l0]); glds16(b1, &Bs[stg][l1]);
      a0 += 32; a1 += 32; b0 += 32; b1 += 32;
    }
    FragU bw[4];
#pragma unroll
    for (int n = 0; n < 4; ++n)
      bw[n].u = *(const uint4*)&Bs[cur][(fq * 256 + wc + n * 16 + fr) * 8];
    __builtin_amdgcn_s_setprio(1);
#pragma unroll
    for (int m = 0; m < 8; ++m) {
      FragU af;
      af.u = *(const uint4*)&As[cur][(fq * 256 + wr + m * 16 + fr) * 8];
#pragma unroll
      for (int n = 0; n < 4; ++n)
        acc[m][n] = MFMA_BF16(af.b, bw[n].b, acc[m][n]);
    }
    __builtin_amdgcn_s_setprio(0);
    if (t + 2 < nt) asm volatile("s_waitcnt vmcnt(4)" ::: "memory");
    else            asm volatile("s_waitcnt vmcnt(0)" ::: "memory");
    __builtin_amdgcn_s_barrier();
    cur = cur + 1; if (cur == 3) cur = 0;
  }
  // epilogue: j base for this wave = (n0 + wc)/2; n=0,1 gate, n=2,3 up
  const int jb = (n0 + wc) >> 1;
#pragma unroll
  for (int m = 0; m < 8; ++m) {
#pragma unroll
    for (int r = 0; r < 4; ++r) {
      int gm = m0 + wr + m * 16 + fq * 4 + r;
      if (gm < M) {
#pragma unroll
        for (int n = 0; n < 2; ++n) {
          int j = jb + n * 16 + fr;
          float g = acc[m][n][r];
          float u = acc[m][n + 2][r];
          float s = g / (1.f + __expf(-g));
          outb[(size_t)gm * 4096 + j] = (bf16_t)(s * u);
        }
      }
    }
  }
}

// ------------------------------------------------------------------ launch
extern "C" void kernel_launch(void* const* d_in, const int* in_sizes, int n_in,
                              void* d_out, int out_size, void* d_ws, size_t ws_size,
                              hipStream_t stream) {
  (void)in_sizes; (void)n_in; (void)out_size;
  const float* pixel     = (const float*)d_in[0];
  const int*   pos_ids   = (const int*)d_in[1];
  const float* w_patch   = (const float*)d_in[3];
  const float* qkv_w     = (const float*)d_in[4];
  const float* qkv_b     = (const float*)d_in[5];
  const float* q_norm_w  = (const float*)d_in[6];
  const float* k_norm_w  = (const float*)d_in[7];
  const float* proj_w    = (const float*)d_in[8];
  const float* proj_b    = (const float*)d_in[9];
  const float* norm1_w   = (const float*)d_in[10];
  const float* norm2_w   = (const float*)d_in[11];
  const float* gate_w    = (const float*)d_in[12];
  const float* up_w      = (const float*)d_in[13];
  const float* down_w    = (const float*)d_in[14];
  const float* post_ln_w = (const float*)d_in[15];
  const float* conv_w    = (const float*)d_in[16];
  const float* conv_b    = (const float*)d_in[17];
  const float* fc1_w     = (const float*)d_in[18];
  const float* fc1_b     = (const float*)d_in[19];
  const float* fc2_w     = (const float*)d_in[20];
  const float* fc2_b     = (const float*)d_in[21];
  float* out = (float*)d_out;

  char* wsb = (char*)d_ws;
  float*  h     = (float*)(wsb + 0);            // 9,830,400 B
  bf16_t* xo    = (bf16_t*)(wsb + 9830400);     // 4,915,200 B (x / o shared)
  char*   R1    = wsb + 14745600;               // 29,491,200 B multi-use
  bf16_t* qkvb  = (bf16_t*)(R1);
  bf16_t* qb    = (bf16_t*)(R1 + 14745600);
  bf16_t* kb    = (bf16_t*)(R1 + 19660800);
  bf16_t* vb    = (bf16_t*)(R1 + 24576000);
  bf16_t* gub   = (bf16_t*)(R1);                // 13,107,200 B activated gate*up
  bf16_t* pixb  = (bf16_t*)(R1);
  bf16_t* ab    = (bf16_t*)(R1);
  bf16_t* dbuf  = (bf16_t*)(R1 + 4915200);
  bf16_t* ebuf  = (bf16_t*)(R1 + 6144000);
  float*  skp   = (float*)(R1 + 11059200);      // 9,830,400 B split-K partials (head)
  float*  cosb  = (float*)(wsb + 44236800);     // 819,200 B
  float*  sinb  = (float*)(wsb + 45056000);     // 819,200 B
  char*   W     = wsb + 45875200;               // 56,623,104 B (per-layer bf16 weights)
  bf16_t* qkvwT = (bf16_t*)(W);
  bf16_t* projT = (bf16_t*)(W + 14155776);
  bf16_t* gateupT = (bf16_t*)(W + 18874368);    // (8192,1536) interleaved gate|up
  bf16_t* downT = (bf16_t*)(W + 44040192);
  bf16_t* convB = (bf16_t*)(W);
  bf16_t* fc1T  = (bf16_t*)(W + 18874368);
  bf16_t* fc2T  = (bf16_t*)(W + 37748736);
  bf16_t* wpT   = (bf16_t*)(wsb + 102498304);   // 3,637,248 B, ends 106,135,552
  float*  skp2  = (float*)(wsb + 106135552);    // 19,660,800 B split-K(2) partials
  const bool big_ws = ws_size >= (size_t)106135552 + 19660800;

  rope_k<<<1600, 64, 0, stream>>>(pos_ids, cosb, sinb);
  convert_pad_k<<<(1600 * 1184 + 255) / 256, 256, 0, stream>>>(pixel, pixb, 1600, 1176, 1184);
  transpose_cvt_k<<<dim3(37, 48), 256, 0, stream>>>(w_patch, wpT, 1176, 1536, 1184);
  gemm64<0, 0, 0, 0><<<dim3(24, 25), 256, 0, stream>>>(
      pixb, wpT, nullptr, nullptr, h, nullptr, 1600, 1536, 1184, 1184);

  for (int l = 0; l < 4; ++l) {
    const float* qw = qkv_w  + (size_t)l * 1536 * 4608;
    const float* pw = proj_w + (size_t)l * 1536 * 1536;
    const float* gw = gate_w + (size_t)l * 1536 * 4096;
    const float* uw = up_w   + (size_t)l * 1536 * 4096;
    const float* dw = down_w + (size_t)l * 4096 * 1536;
    transpose_cvt_k<<<dim3(48, 144), 256, 0, stream>>>(qw, qkvwT, 1536, 4608, 1536);
    transpose_cvt_k<<<dim3(48, 48),  256, 0, stream>>>(pw, projT, 1536, 1536, 1536);
    transpose_cvt_gu_k<<<dim3(48, 128), 256, 0, stream>>>(gw, gateupT, 1536, 4096, 1536, 0);
    transpose_cvt_gu_k<<<dim3(48, 128), 256, 0, stream>>>(uw, gateupT, 1536, 4096, 1536, 32);
    transpose_cvt_k<<<dim3(128, 48), 256, 0, stream>>>(dw, downT, 4096, 1536, 4096);

    rmsnorm_bf_k<<<1600, 256, 0, stream>>>(h, norm1_w + (size_t)l * 1536, xo, 1536);
    gemm128<0, 1, 0, 1><<<dim3(36, 13), 256, 0, stream>>>(
        xo, qkvwT, qkv_b + (size_t)l * 4608, nullptr, nullptr, qkvb, 1600, 4608, 1536, 1536);
    qknorm_rope_k<<<1600 * 12, 128, 0, stream>>>(
        qkvb, q_norm_w + (size_t)l * 128, k_norm_w + (size_t)l * 128, cosb, sinb, qb, kb);
    vtrans_k<<<dim3(12, 13), 256, 0, stream>>>(qkvb, vb);
    attn_mfma<<<300, 256, 0, stream>>>(qb, kb, vb, xo);
    if (big_ws) {
      gemm128sk<2><<<dim3(12, 13, 2), 256, 0, stream>>>(
          xo, projT, skp2, 1600, 1536, 1536, 1536);
      reduce2_res<1><<<(1600 * 1536 + 255) / 256, 256, 0, stream>>>(
          skp2, proj_b + (size_t)l * 1536, h, 1600, 1536);
    } else {
      gemm64<0, 1, 1, 0><<<dim3(24, 25), 256, 0, stream>>>(
          xo, projT, proj_b + (size_t)l * 1536, h, h, nullptr, 1600, 1536, 1536, 1536);
    }
    rmsnorm_bf_k<<<1600, 256, 0, stream>>>(h, norm2_w + (size_t)l * 1536, xo, 1536);
    gemm256gu<<<dim3(32, 7), 512, 0, stream>>>(
        xo, gateupT, gub, 1600, 1536, 1536);
    if (big_ws) {
      gemm128sk<2><<<dim3(12, 13, 2), 256, 0, stream>>>(
          gub, downT, skp2, 1600, 1536, 4096, 4096);
      reduce2_res<0><<<(1600 * 1536 + 255) / 256, 256, 0, stream>>>(
          skp2, nullptr, h, 1600, 1536);
    } else {
      gemm64<0, 0, 1, 0><<<dim3(24, 25), 256, 0, stream>>>(
          gub, downT, nullptr, h, h, nullptr, 1600, 1536, 4096, 4096);
    }
  }

  // head
  convert_pad_k<<<(1536 * 6144 + 255) / 256, 256, 0, stream>>>(conv_w, convB, 1536, 6144, 6144);
  transpose_cvt_k<<<dim3(48, 192), 256, 0, stream>>>(fc1_w, fc1T, 1536, 6144, 1536);
  transpose_cvt_k<<<dim3(192, 48), 256, 0, stream>>>(fc2_w, fc2T, 6144, 1536, 6144);
  rmsnorm_bf_k<<<1600, 256, 0, stream>>>(h, post_ln_w, xo, 1536);
  gather_conv_k<<<(400 * 6144 + 255) / 256, 256, 0, stream>>>(xo, ab);
  gemm64sk<4><<<dim3(24, 7, 4), 256, 0, stream>>>(ab, convB, skp, 400, 1536, 6144, 6144);
  reduce_sk<4, 0, 1><<<(400 * 1536 + 255) / 256, 256, 0, stream>>>(
      skp, conv_b, nullptr, dbuf, 400, 1536);
  gemm64<1, 1, 0, 1><<<dim3(96, 7), 256, 0, stream>>>(
      dbuf, fc1T, fc1_b, nullptr, nullptr, ebuf, 400, 6144, 1536, 1536);
  gemm64sk<4><<<dim3(24, 7, 4), 256, 0, stream>>>(ebuf, fc2T, skp, 400, 1536, 6144, 6144);
  reduce_sk<4, 0, 0><<<(400 * 1536 + 255) / 256, 256, 0, stream>>>(
      skp, fc2_b, out, nullptr, 400, 1536);
}

// Round 24
// 1865.495 us; speedup vs baseline: 1.0924x; 1.0664x over previous
//
#include <hip/hip_runtime.h>
#include <math.h>

typedef __bf16 bf16_t;
typedef float f32x4 __attribute__((ext_vector_type(4)));
typedef __bf16 bf16x8 __attribute__((ext_vector_type(8)));

union FragU { uint4 u; bf16x8 b; };

#define MFMA_BF16(a, b, c) __builtin_amdgcn_mfma_f32_16x16x32_bf16((a), (b), (c), 0, 0, 0)

__device__ __forceinline__ void glds16(const void* g, void* l) {
  __builtin_amdgcn_global_load_lds((const __attribute__((address_space(1))) void*)g,
                                   (__attribute__((address_space(3))) void*)l, 16, 0, 0);
}

// ------------------------------------------------------------------ rope tables (fp32)
__global__ void rope_k(const int* __restrict__ pos_ids, float* __restrict__ cosb,
                       float* __restrict__ sinb) {
  int s = blockIdx.x;
  int d = threadIdx.x;            // 0..63
  int pair = d >> 5, j = d & 31;
  float p = (float)pos_ids[s * 2 + pair];
  float inv = powf(10000.f, -(float)j / 32.f);
  float v = p * inv;
  float c = cosf(v), sn = sinf(v);
  cosb[s * 128 + d] = c;  cosb[s * 128 + d + 64] = c;
  sinb[s * 128 + d] = sn; sinb[s * 128 + d + 64] = sn;
}

// ------------------------------------------------------------------ rmsnorm fp32 -> bf16
__global__ __launch_bounds__(256) void rmsnorm_bf_k(const float* __restrict__ in,
                                                    const float* __restrict__ w,
                                                    bf16_t* __restrict__ out, int cols) {
  int row = blockIdx.x;
  const float* x = in + (size_t)row * cols;
  float ss = 0.f;
  for (int c = threadIdx.x; c < cols; c += 256) { float v = x[c]; ss = fmaf(v, v, ss); }
#pragma unroll
  for (int o = 32; o; o >>= 1) ss += __shfl_xor(ss, o);
  __shared__ float red[4];
  if ((threadIdx.x & 63) == 0) red[threadIdx.x >> 6] = ss;
  __syncthreads();
  float tot = red[0] + red[1] + red[2] + red[3];
  float rs = rsqrtf(tot / (float)cols + 1e-6f);
  bf16_t* y = out + (size_t)row * cols;
  for (int c = threadIdx.x; c < cols; c += 256) y[c] = (bf16_t)(x[c] * rs * w[c]);
}

// ------------------------------------------------------------------ transpose+convert v2: 64x64 tile, float4 loads, bf16x8 stores.
// in (K,N) f32 -> out (N,Kpad) bf16, zero-pad k>=K. N%64==0, Kpad%8==0.
__global__ __launch_bounds__(256) void transpose_cvt_v2(const float* __restrict__ in,
                                                        bf16_t* __restrict__ out,
                                                        int K, int N, int Kpad) {
  __shared__ float t[64][65];
  const int k0 = blockIdx.x * 64, n0 = blockIdx.y * 64;
  const int tx = threadIdx.x & 15, ty = threadIdx.x >> 4;   // tx:n/4, ty:k row
#pragma unroll
  for (int i = 0; i < 4; ++i) {
    int k = k0 + ty + 16 * i;
    float4 v = {0.f, 0.f, 0.f, 0.f};
    if (k < K) v = *(const float4*)&in[(size_t)k * N + n0 + tx * 4];
    t[ty + 16 * i][tx * 4 + 0] = v.x;
    t[ty + 16 * i][tx * 4 + 1] = v.y;
    t[ty + 16 * i][tx * 4 + 2] = v.z;
    t[ty + 16 * i][tx * 4 + 3] = v.w;
  }
  __syncthreads();
  const int nn = threadIdx.x >> 3;        // 0..31
  const int kc = (threadIdx.x & 7) * 8;   // 0..56
  if (k0 + kc < Kpad) {
#pragma unroll
    for (int p = 0; p < 2; ++p) {
      int n = n0 + nn + p * 32;
      bf16_t tmp[8];
#pragma unroll
      for (int j = 0; j < 8; ++j) tmp[j] = (bf16_t)t[kc + j][nn + p * 32];
      *(uint4*)&out[(size_t)n * Kpad + k0 + kc] = *(uint4*)tmp;
    }
  }
}

// ------------------------------------------------------------------ transpose+convert v2 for interleaved gate|up weights:
// dst row = (n/32)*64 + grpoff + (n%32)  (grpoff 0 = gate, 32 = up)
__global__ __launch_bounds__(256) void transpose_cvt_gu_v2(const float* __restrict__ in,
                                                           bf16_t* __restrict__ out,
                                                           int K, int N, int Kpad, int grpoff) {
  __shared__ float t[64][65];
  const int k0 = blockIdx.x * 64, n0 = blockIdx.y * 64;
  const int tx = threadIdx.x & 15, ty = threadIdx.x >> 4;
#pragma unroll
  for (int i = 0; i < 4; ++i) {
    int k = k0 + ty + 16 * i;
    float4 v = {0.f, 0.f, 0.f, 0.f};
    if (k < K) v = *(const float4*)&in[(size_t)k * N + n0 + tx * 4];
    t[ty + 16 * i][tx * 4 + 0] = v.x;
    t[ty + 16 * i][tx * 4 + 1] = v.y;
    t[ty + 16 * i][tx * 4 + 2] = v.z;
    t[ty + 16 * i][tx * 4 + 3] = v.w;
  }
  __syncthreads();
  const int nn = threadIdx.x >> 3;
  const int kc = (threadIdx.x & 7) * 8;
  if (k0 + kc < Kpad) {
#pragma unroll
    for (int p = 0; p < 2; ++p) {
      int n = n0 + nn + p * 32;
      int row = ((n >> 5) << 6) + grpoff + (n & 31);
      bf16_t tmp[8];
#pragma unroll
      for (int j = 0; j < 8; ++j) tmp[j] = (bf16_t)t[kc + j][nn + p * 32];
      *(uint4*)&out[(size_t)row * Kpad + k0 + kc] = *(uint4*)tmp;
    }
  }
}

// ------------------------------------------------------------------ straight convert with K-pad: in (R,K) f32 -> out (R,Kpad) bf16
__global__ void convert_pad_k(const float* __restrict__ in, bf16_t* __restrict__ out,
                              int R, int K, int Kpad) {
  int idx = blockIdx.x * 256 + threadIdx.x;
  if (idx < R * Kpad) {
    int r = idx / Kpad, k = idx - r * Kpad;
    out[idx] = (k < K) ? (bf16_t)in[(size_t)r * K + k] : (bf16_t)0.f;
  }
}

// ------------------------------------------------------------------ vectorized straight convert (no pad): 8 elems/thread
__global__ void convert8_k(const float* __restrict__ in, bf16_t* __restrict__ out, int n8) {
  int i = blockIdx.x * 256 + threadIdx.x;
  if (i < n8) {
    float4 a = ((const float4*)in)[2 * i];
    float4 b = ((const float4*)in)[2 * i + 1];
    bf16_t tmp[8] = {(bf16_t)a.x, (bf16_t)a.y, (bf16_t)a.z, (bf16_t)a.w,
                     (bf16_t)b.x, (bf16_t)b.y, (bf16_t)b.z, (bf16_t)b.w};
    ((uint4*)out)[i] = *(uint4*)tmp;
  }
}

// ------------------------------------------------------------------ qk rmsnorm + rope: qkv bf16 -> q_bf (scaled, [h][s][d]), k_bf
__global__ __launch_bounds__(128) void qknorm_rope_k(const bf16_t* __restrict__ qkv,
    const float* __restrict__ qn, const float* __restrict__ kn,
    const float* __restrict__ cosb, const float* __restrict__ sinb,
    bf16_t* __restrict__ qo, bf16_t* __restrict__ ko) {
  const int s = blockIdx.x / 12, h = blockIdx.x % 12;
  const int d = threadIdx.x;  // 0..127
  __shared__ float nrm[128];
  __shared__ float red[2];
  const float cs = cosb[s * 128 + d], sn = sinb[s * 128 + d];
  const float QS = 0.08838834764831845f * 1.4426950408889634f;  // D^-0.5 * log2(e)
#pragma unroll
  for (int part = 0; part < 2; ++part) {
    const bf16_t* p = qkv + (size_t)s * 4608 + part * 1536 + h * 128;
    float v = (float)p[d];
    float ss = v * v;
#pragma unroll
    for (int o = 32; o; o >>= 1) ss += __shfl_xor(ss, o);
    if ((d & 63) == 0) red[d >> 6] = ss;
    __syncthreads();
    float rs = rsqrtf((red[0] + red[1]) * (1.f / 128.f) + 1e-6f);
    float nv = v * rs * (part ? kn[d] : qn[d]);
    nrm[d] = nv;
    __syncthreads();
    float rot = (d < 64) ? -nrm[d + 64] : nrm[d - 64];
    float val = nv * cs + rot * sn;
    bf16_t* dst = part ? ko : qo;
    dst[((size_t)h * 1600 + s) * 128 + d] = (bf16_t)(part ? val : val * QS);
    __syncthreads();
  }
}

// ------------------------------------------------------------------ v transpose: qkv bf16 [s][2C + h*128 + d] -> vt [h][d][s]
__global__ __launch_bounds__(256) void vtrans_k(const bf16_t* __restrict__ qkv,
                                                bf16_t* __restrict__ vt) {
  __shared__ __align__(16) bf16_t t[128][136];
  const int h = blockIdx.x, s0 = blockIdx.y * 128;
  const int tx = threadIdx.x & 15, ty = threadIdx.x >> 4;
#pragma unroll
  for (int i = 0; i < 8; ++i) {
    int sl = ty + 16 * i, s = s0 + sl;
    uint4 v = {0u, 0u, 0u, 0u};
    if (s < 1600) v = *(const uint4*)&qkv[(size_t)s * 4608 + 3072 + h * 128 + tx * 8];
    *(uint4*)&t[sl][tx * 8] = v;
  }
  __syncthreads();
  if (s0 + tx * 8 < 1600) {
#pragma unroll
    for (int i = 0; i < 8; ++i) {
      int dd = ty + 16 * i;
      bf16_t tmp[8];
#pragma unroll
      for (int j = 0; j < 8; ++j) tmp[j] = t[tx * 8 + j][dd];
      *(uint4*)&vt[(size_t)(h * 128 + dd) * 1600 + s0 + tx * 8] = *(uint4*)tmp;
    }
  }
}

// ------------------------------------------------------------------ flash attention, LDS-staged K/V shared by 4 waves (64 q-rows/block),
// 3-buffer counted-vmcnt pipeline. Fixed-max softmax:
// score*log2e <= sqrt(128)*log2e = 16.33 -> p = exp2(s-16), no running max.
__global__ __launch_bounds__(256) void attn_mfma(const bf16_t* __restrict__ qg,
    const bf16_t* __restrict__ kg, const bf16_t* __restrict__ vg,
    bf16_t* __restrict__ o) {
  const int bid = blockIdx.x;                 // grid 300 = 12h * 25 qtiles
  const int xcd = bid & 7, sub = bid >> 3;
  const int swz = (xcd < 4 ? xcd * 38 : 4 * 38 + (xcd - 4) * 37) + sub;
  const int h = swz / 25;
  const int q0 = (swz % 25) * 64;
  const int tid = threadIdx.x;       // 0..255
  const int w = tid >> 6, lane = tid & 63;
  const int fq = lane >> 4, fr = lane & 15;
  const bf16_t* qh = qg + (size_t)h * 1600 * 128;
  const bf16_t* kh = kg + (size_t)h * 1600 * 128;
  const bf16_t* vh = vg + (size_t)h * 128 * 1600;
  __shared__ __align__(16) bf16_t Ks[3][4096];   // [cb16][key32][8]
  __shared__ __align__(16) bf16_t Vs[3][4096];   // [cb4][d128][8]
  __shared__ __align__(16) bf16_t pl[4][512];    // per-wave P [cb4][q16][8]
  int off_k[2], off_v[2], ldsb[2];
#pragma unroll
  for (int c = 0; c < 2; ++c) {
    int j = c * 256 + tid;
    off_k[c] = (j & 31) * 128 + (j >> 5) * 8;
    off_v[c] = (j & 127) * 1600 + (j >> 7) * 8;
    ldsb[c] = (c * 256 + w * 64) * 8;
  }
  FragU aq[4];
#pragma unroll
  for (int db = 0; db < 4; ++db)
    aq[db].u = *(const uint4*)&qh[(size_t)(q0 + w * 16 + fr) * 128 + db * 32 + fq * 8];
  f32x4 zero = {0.f, 0.f, 0.f, 0.f};
  f32x4 oacc[8];
#pragma unroll
  for (int nb = 0; nb < 8; ++nb) oacc[nb] = zero;
  float lrun[4] = {0.f, 0.f, 0.f, 0.f};
#pragma unroll
  for (int c = 0; c < 2; ++c) {
    glds16(kh + off_k[c], &Ks[0][ldsb[c]]);
    glds16(vh + off_v[c], &Vs[0][ldsb[c]]);
  }
#pragma unroll
  for (int c = 0; c < 2; ++c) {
    glds16(kh + 32 * 128 + off_k[c], &Ks[1][ldsb[c]]);
    glds16(vh + 32 + off_v[c], &Vs[1][ldsb[c]]);
  }
  asm volatile("s_waitcnt vmcnt(4)" ::: "memory");
  __builtin_amdgcn_s_barrier();
  int cur = 0;
  for (int t = 0; t < 50; ++t) {
    int stg = cur + 2; if (stg >= 3) stg -= 3;
    if (t + 2 < 50) {
      const int kb = (t + 2) * 32;
#pragma unroll
      for (int c = 0; c < 2; ++c) {
        glds16(kh + (size_t)kb * 128 + off_k[c], &Ks[stg][ldsb[c]]);
        glds16(vh + kb + off_v[c], &Vs[stg][ldsb[c]]);
      }
    }
    f32x4 s0 = zero, s1 = zero;
#pragma unroll
    for (int db = 0; db < 4; ++db) {
      FragU bk0, bk1;
      bk0.u = *(const uint4*)&Ks[cur][((db * 4 + fq) * 32 + fr) * 8];
      bk1.u = *(const uint4*)&Ks[cur][((db * 4 + fq) * 32 + 16 + fr) * 8];
      s0 = MFMA_BF16(aq[db].b, bk0.b, s0);
      s1 = MFMA_BF16(aq[db].b, bk1.b, s1);
    }
    float p0[4], p1[4];
#pragma unroll
    for (int r = 0; r < 4; ++r) {
      p0[r] = exp2f(s0[r] - 16.f);
      p1[r] = exp2f(s1[r] - 16.f);
      lrun[r] += p0[r] + p1[r];
    }
#pragma unroll
    for (int r = 0; r < 4; ++r) {
      int q = fq * 4 + r;
      int kk0 = fr;
      pl[w][((kk0 >> 3) * 16 + q) * 8 + (kk0 & 7)] = (bf16_t)p0[r];
      int kk1 = 16 + fr;
      pl[w][((kk1 >> 3) * 16 + q) * 8 + (kk1 & 7)] = (bf16_t)p1[r];
    }
    FragU ap;
    ap.u = *(const uint4*)&pl[w][(fq * 16 + fr) * 8];
#pragma unroll
    for (int nb = 0; nb < 8; ++nb) {
      FragU bv;
      bv.u = *(const uint4*)&Vs[cur][(fq * 128 + nb * 16 + fr) * 8];
      oacc[nb] = MFMA_BF16(ap.b, bv.b, oacc[nb]);
    }
    if (t + 2 < 50) asm volatile("s_waitcnt vmcnt(4)" ::: "memory");
    else            asm volatile("s_waitcnt vmcnt(0)" ::: "memory");
    __builtin_amdgcn_s_barrier();
    cur = cur + 1; if (cur == 3) cur = 0;
  }
#pragma unroll
  for (int r = 0; r < 4; ++r) {
    lrun[r] += __shfl_xor(lrun[r], 1);
    lrun[r] += __shfl_xor(lrun[r], 2);
    lrun[r] += __shfl_xor(lrun[r], 4);
    lrun[r] += __shfl_xor(lrun[r], 8);
  }
  float inv_[4];
#pragma unroll
  for (int r = 0; r < 4; ++r) inv_[r] = 1.f / lrun[r];
#pragma unroll
  for (int nb = 0; nb < 8; ++nb)
#pragma unroll
    for (int r = 0; r < 4; ++r) {
      int qq = q0 + w * 16 + fq * 4 + r;
      o[(size_t)qq * 1536 + h * 128 + nb * 16 + fr] = (bf16_t)(oacc[nb][r] * inv_[r]);
    }
}

// ------------------------------------------------------------------ gather for conv-as-GEMM (bf16)
__global__ void gather_conv_k(const bf16_t* __restrict__ hf, bf16_t* __restrict__ abuf) {
  int idx = blockIdx.x * 256 + threadIdx.x;  // 400*6144
  if (idx < 400 * 6144) {
    int n = idx / 6144, k = idx - n * 6144;
    abuf[idx] = hf[(size_t)(4 * n + (k & 3)) * 1536 + (k >> 2)];
  }
}

// ------------------------------------------------------------------ 64x64-tile bf16 MFMA GEMM, 3-buffer counted-vmcnt pipeline
template <int ACT, int BIAS, int RES, int OBF>
__global__ __launch_bounds__(256) void gemm64(const bf16_t* __restrict__ A,
    const bf16_t* __restrict__ Bt, const float* __restrict__ bias,
    const float* __restrict__ res, float* __restrict__ outf,
    bf16_t* __restrict__ outb, int M, int N, int K, int lda) {
  __shared__ __align__(16) bf16_t As[3][2048];  // [buf][cb4][row64][8]
  __shared__ __align__(16) bf16_t Bs[3][2048];
  const int tid = threadIdx.x;
  const int lane = tid & 63, w = tid >> 6;
  const int m0 = blockIdx.y * 64, n0 = blockIdx.x * 64;
  const int fq = lane >> 4, fr = lane & 15;
  const int wc = w * 16;
  const bf16_t* ag = A + (size_t)(m0 + lane) * lda + w * 8;
  const bf16_t* bg = Bt + (size_t)(n0 + lane) * K + w * 8;
  f32x4 zero = {0.f, 0.f, 0.f, 0.f};
  f32x4 acc[4];
#pragma unroll
  for (int m = 0; m < 4; ++m) acc[m] = zero;
  const int nt = K >> 5;
  glds16(ag, &As[0][w * 512]); glds16(bg, &Bs[0][w * 512]);
  ag += 32; bg += 32;
  glds16(ag, &As[1][w * 512]); glds16(bg, &Bs[1][w * 512]);
  ag += 32; bg += 32;
  asm volatile("s_waitcnt vmcnt(2)" ::: "memory");
  __builtin_amdgcn_s_barrier();
  int cur = 0;
  for (int t = 0; t < nt; ++t) {
    int stg = cur + 2; if (stg >= 3) stg -= 3;
    if (t + 2 < nt) {
      glds16(ag, &As[stg][w * 512]); glds16(bg, &Bs[stg][w * 512]);
      ag += 32; bg += 32;
    }
    FragU bw, af[4];
    bw.u = *(const uint4*)&Bs[cur][(fq * 64 + wc + fr) * 8];
#pragma unroll
    for (int m = 0; m < 4; ++m)
      af[m].u = *(const uint4*)&As[cur][(fq * 64 + m * 16 + fr) * 8];
#pragma unroll
    for (int m = 0; m < 4; ++m)
      acc[m] = MFMA_BF16(af[m].b, bw.b, acc[m]);
    if (t + 2 < nt) asm volatile("s_waitcnt vmcnt(2)" ::: "memory");
    else            asm volatile("s_waitcnt vmcnt(0)" ::: "memory");
    __builtin_amdgcn_s_barrier();
    cur = cur + 1; if (cur == 3) cur = 0;
  }
#pragma unroll
  for (int m = 0; m < 4; ++m) {
#pragma unroll
    for (int r = 0; r < 4; ++r) {
      int gm = m0 + m * 16 + fq * 4 + r;
      if (gm < M) {
        int gn = n0 + wc + fr;
        float v = acc[m][r];
        if (BIAS) v += bias[gn];
        if (ACT == 1) {
          float x = v;
          float t = 0.7978845608028654f * fmaf(0.044715f * x, x * x, x);
          float e = exp2f(t * 2.8853900817779268f);   // exp(2t)
          v = x * e / (e + 1.f);                       // 0.5x(1+tanh t)
        }
        if (RES) v += res[(size_t)gm * N + gn];
        if (OBF) outb[(size_t)gm * N + gn] = (bf16_t)v;
        else outf[(size_t)gm * N + gn] = v;
      }
    }
  }
}

// ------------------------------------------------------------------ 64x64-tile split-K GEMM: blockIdx.z covers K-chunk; fp32 partials.
template <int KS>
__global__ __launch_bounds__(256) void gemm64sk(const bf16_t* __restrict__ A,
    const bf16_t* __restrict__ Bt, float* __restrict__ part,
    int M, int N, int K, int lda) {
  __shared__ __align__(16) bf16_t As[3][2048];
  __shared__ __align__(16) bf16_t Bs[3][2048];
  const int tid = threadIdx.x;
  const int lane = tid & 63, w = tid >> 6;
  const int m0 = blockIdx.y * 64, n0 = blockIdx.x * 64;
  const int fq = lane >> 4, fr = lane & 15;
  const int wc = w * 16;
  const int kchunk = K / KS;
  const int kbase = blockIdx.z * kchunk;
  const bf16_t* ag = A + (size_t)(m0 + lane) * lda + kbase + w * 8;
  const bf16_t* bg = Bt + (size_t)(n0 + lane) * K + kbase + w * 8;
  f32x4 zero = {0.f, 0.f, 0.f, 0.f};
  f32x4 acc[4];
#pragma unroll
  for (int m = 0; m < 4; ++m) acc[m] = zero;
  const int nt = kchunk >> 5;
  glds16(ag, &As[0][w * 512]); glds16(bg, &Bs[0][w * 512]);
  ag += 32; bg += 32;
  glds16(ag, &As[1][w * 512]); glds16(bg, &Bs[1][w * 512]);
  ag += 32; bg += 32;
  asm volatile("s_waitcnt vmcnt(2)" ::: "memory");
  __builtin_amdgcn_s_barrier();
  int cur = 0;
  for (int t = 0; t < nt; ++t) {
    int stg = cur + 2; if (stg >= 3) stg -= 3;
    if (t + 2 < nt) {
      glds16(ag, &As[stg][w * 512]); glds16(bg, &Bs[stg][w * 512]);
      ag += 32; bg += 32;
    }
    FragU bw, af[4];
    bw.u = *(const uint4*)&Bs[cur][(fq * 64 + wc + fr) * 8];
#pragma unroll
    for (int m = 0; m < 4; ++m)
      af[m].u = *(const uint4*)&As[cur][(fq * 64 + m * 16 + fr) * 8];
#pragma unroll
    for (int m = 0; m < 4; ++m)
      acc[m] = MFMA_BF16(af[m].b, bw.b, acc[m]);
    if (t + 2 < nt) asm volatile("s_waitcnt vmcnt(2)" ::: "memory");
    else            asm volatile("s_waitcnt vmcnt(0)" ::: "memory");
    __builtin_amdgcn_s_barrier();
    cur = cur + 1; if (cur == 3) cur = 0;
  }
  float* ps = part + (size_t)blockIdx.z * M * N;
#pragma unroll
  for (int m = 0; m < 4; ++m) {
#pragma unroll
    for (int r = 0; r < 4; ++r) {
      int gm = m0 + m * 16 + fq * 4 + r;
      if (gm < M) {
        int gn = n0 + wc + fr;
        ps[(size_t)gm * N + gn] = acc[m][r];
      }
    }
  }
}

// ------------------------------------------------------------------ split-K reduce: sum KS slices + bias (+GELU), write bf16 or fp32
template <int KS, int ACT, int OBF>
__global__ void reduce_sk(const float* __restrict__ part, const float* __restrict__ bias,
                          float* __restrict__ outf, bf16_t* __restrict__ outb,
                          int M, int N) {
  int idx = blockIdx.x * 256 + threadIdx.x;
  if (idx < M * N) {
    int n = idx % N;
    float v = 0.f;
#pragma unroll
    for (int s = 0; s < KS; ++s) v += part[(size_t)s * M * N + idx];
    v += bias[n];
    if (ACT == 1) {
      float x = v;
      float t = 0.7978845608028654f * fmaf(0.044715f * x, x * x, x);
      float e = exp2f(t * 2.8853900817779268f);
      v = x * e / (e + 1.f);
    }
    if (OBF) outb[idx] = (bf16_t)v;
    else outf[idx] = v;
  }
}

// ------------------------------------------------------------------ split-K(2) reduce with residual accumulate into h (+optional bias)
template <int BIAS>
__global__ void reduce2_res(const float* __restrict__ part, const float* __restrict__ bias,
                            float* __restrict__ hio, int M, int N) {
  int idx = blockIdx.x * 256 + threadIdx.x;
  if (idx < M * N) {
    float v = part[idx] + part[(size_t)M * N + idx];
    if (BIAS) v += bias[idx % N];
    hio[idx] += v;
  }
}

// ------------------------------------------------------------------ 128x128-tile bf16 MFMA GEMM, 3-buffer counted-vmcnt pipeline (AI=64)
template <int ACT, int BIAS, int RES, int OBF>
__global__ __launch_bounds__(256) void gemm128(const bf16_t* __restrict__ A,
    const bf16_t* __restrict__ Bt, const float* __restrict__ bias,
    const float* __restrict__ res, float* __restrict__ outf,
    bf16_t* __restrict__ outb, int M, int N, int K, int lda) {
  __shared__ __align__(16) bf16_t As[3][4096];  // [buf][cb4][row128][8]
  __shared__ __align__(16) bf16_t Bs[3][4096];
  const int tid = threadIdx.x;
  const int lane = tid & 63, w = tid >> 6;
  const int m0 = blockIdx.y * 128, n0 = blockIdx.x * 128;
  const int wr = (w >> 1) * 64, wc = (w & 1) * 64;
  const int fq = lane >> 4, fr = lane & 15;
  const int u1 = w * 64 + lane, u2 = u1 + 256;
  const int r1 = u1 & 127, c1 = u1 >> 7;
  const int r2 = u2 & 127, c2 = u2 >> 7;
  const bf16_t* a1 = A + (size_t)(m0 + r1) * lda + c1 * 8;
  const bf16_t* a2 = A + (size_t)(m0 + r2) * lda + c2 * 8;
  const bf16_t* b1 = Bt + (size_t)(n0 + r1) * K + c1 * 8;
  const bf16_t* b2 = Bt + (size_t)(n0 + r2) * K + c2 * 8;
  f32x4 zero = {0.f, 0.f, 0.f, 0.f};
  f32x4 acc[4][4];
#pragma unroll
  for (int m = 0; m < 4; ++m)
#pragma unroll
    for (int n = 0; n < 4; ++n) acc[m][n] = zero;
  const int nt = K >> 5;
  glds16(a1, &As[0][w * 512]); glds16(a2, &As[0][2048 + w * 512]);
  glds16(b1, &Bs[0][w * 512]); glds16(b2, &Bs[0][2048 + w * 512]);
  a1 += 32; a2 += 32; b1 += 32; b2 += 32;
  glds16(a1, &As[1][w * 512]); glds16(a2, &As[1][2048 + w * 512]);
  glds16(b1, &Bs[1][w * 512]); glds16(b2, &Bs[1][2048 + w * 512]);
  a1 += 32; a2 += 32; b1 += 32; b2 += 32;
  asm volatile("s_waitcnt vmcnt(4)" ::: "memory");
  __builtin_amdgcn_s_barrier();
  int cur = 0;
  for (int t = 0; t < nt; ++t) {
    int stg = cur + 2; if (stg >= 3) stg -= 3;
    if (t + 2 < nt) {
      glds16(a1, &As[stg][w * 512]); glds16(a2, &As[stg][2048 + w * 512]);
      glds16(b1, &Bs[stg][w * 512]); glds16(b2, &Bs[stg][2048 + w * 512]);
      a1 += 32; a2 += 32; b1 += 32; b2 += 32;
    }
    FragU af[4], bw[4];
#pragma unroll
    for (int m = 0; m < 4; ++m)
      af[m].u = *(const uint4*)&As[cur][(fq * 128 + wr + m * 16 + fr) * 8];
#pragma unroll
    for (int n = 0; n < 4; ++n)
      bw[n].u = *(const uint4*)&Bs[cur][(fq * 128 + wc + n * 16 + fr) * 8];
#pragma unroll
    for (int m = 0; m < 4; ++m)
#pragma unroll
      for (int n = 0; n < 4; ++n)
        acc[m][n] = MFMA_BF16(af[m].b, bw[n].b, acc[m][n]);
    if (t + 2 < nt) asm volatile("s_waitcnt vmcnt(4)" ::: "memory");
    else            asm volatile("s_waitcnt vmcnt(0)" ::: "memory");
    __builtin_amdgcn_s_barrier();
    cur = cur + 1; if (cur == 3) cur = 0;
  }
#pragma unroll
  for (int m = 0; m < 4; ++m) {
#pragma unroll
    for (int r = 0; r < 4; ++r) {
      int gm = m0 + wr + m * 16 + fq * 4 + r;
      if (gm < M) {
#pragma unroll
        for (int n = 0; n < 4; ++n) {
          int gn = n0 + wc + n * 16 + fr;
          float v = acc[m][n][r];
          if (BIAS) v += bias[gn];
          if (ACT == 1) {
            float x = v;
            float t2 = 0.7978845608028654f * fmaf(0.044715f * x, x * x, x);
            float e = exp2f(t2 * 2.8853900817779268f);
            v = x * e / (e + 1.f);
          }
          if (RES) v += res[(size_t)gm * N + gn];
          if (OBF) outb[(size_t)gm * N + gn] = (bf16_t)v;
          else outf[(size_t)gm * N + gn] = v;
        }
      }
    }
  }
}

// ------------------------------------------------------------------ 128x128-tile split-K GEMM: blockIdx.z covers K-chunk; fp32 partials.
template <int KS>
__global__ __launch_bounds__(256) void gemm128sk(const bf16_t* __restrict__ A,
    const bf16_t* __restrict__ Bt, float* __restrict__ part,
    int M, int N, int K, int lda) {
  __shared__ __align__(16) bf16_t As[3][4096];
  __shared__ __align__(16) bf16_t Bs[3][4096];
  const int tid = threadIdx.x;
  const int lane = tid & 63, w = tid >> 6;
  const int m0 = blockIdx.y * 128, n0 = blockIdx.x * 128;
  const int wr = (w >> 1) * 64, wc = (w & 1) * 64;
  const int fq = lane >> 4, fr = lane & 15;
  const int u1 = w * 64 + lane, u2 = u1 + 256;
  const int r1 = u1 & 127, c1 = u1 >> 7;
  const int r2 = u2 & 127, c2 = u2 >> 7;
  const int kchunk = K / KS;
  const int kbase = blockIdx.z * kchunk;
  const bf16_t* a1 = A + (size_t)(m0 + r1) * lda + kbase + c1 * 8;
  const bf16_t* a2 = A + (size_t)(m0 + r2) * lda + kbase + c2 * 8;
  const bf16_t* b1 = Bt + (size_t)(n0 + r1) * K + kbase + c1 * 8;
  const bf16_t* b2 = Bt + (size_t)(n0 + r2) * K + kbase + c2 * 8;
  f32x4 zero = {0.f, 0.f, 0.f, 0.f};
  f32x4 acc[4][4];
#pragma unroll
  for (int m = 0; m < 4; ++m)
#pragma unroll
    for (int n = 0; n < 4; ++n) acc[m][n] = zero;
  const int nt = kchunk >> 5;
  glds16(a1, &As[0][w * 512]); glds16(a2, &As[0][2048 + w * 512]);
  glds16(b1, &Bs[0][w * 512]); glds16(b2, &Bs[0][2048 + w * 512]);
  a1 += 32; a2 += 32; b1 += 32; b2 += 32;
  glds16(a1, &As[1][w * 512]); glds16(a2, &As[1][2048 + w * 512]);
  glds16(b1, &Bs[1][w * 512]); glds16(b2, &Bs[1][2048 + w * 512]);
  a1 += 32; a2 += 32; b1 += 32; b2 += 32;
  asm volatile("s_waitcnt vmcnt(4)" ::: "memory");
  __builtin_amdgcn_s_barrier();
  int cur = 0;
  for (int t = 0; t < nt; ++t) {
    int stg = cur + 2; if (stg >= 3) stg -= 3;
    if (t + 2 < nt) {
      glds16(a1, &As[stg][w * 512]); glds16(a2, &As[stg][2048 + w * 512]);
      glds16(b1, &Bs[stg][w * 512]); glds16(b2, &Bs[stg][2048 + w * 512]);
      a1 += 32; a2 += 32; b1 += 32; b2 += 32;
    }
    FragU af[4], bw[4];
#pragma unroll
    for (int m = 0; m < 4; ++m)
      af[m].u = *(const uint4*)&As[cur][(fq * 128 + wr + m * 16 + fr) * 8];
#pragma unroll
    for (int n = 0; n < 4; ++n)
      bw[n].u = *(const uint4*)&Bs[cur][(fq * 128 + wc + n * 16 + fr) * 8];
#pragma unroll
    for (int m = 0; m < 4; ++m)
#pragma unroll
      for (int n = 0; n < 4; ++n)
        acc[m][n] = MFMA_BF16(af[m].b, bw[n].b, acc[m][n]);
    if (t + 2 < nt) asm volatile("s_waitcnt vmcnt(4)" ::: "memory");
    else            asm volatile("s_waitcnt vmcnt(0)" ::: "memory");
    __builtin_amdgcn_s_barrier();
    cur = cur + 1; if (cur == 3) cur = 0;
  }
  float* ps = part + (size_t)blockIdx.z * M * N;
#pragma unroll
  for (int m = 0; m < 4; ++m) {
#pragma unroll
    for (int r = 0; r < 4; ++r) {
      int gm = m0 + wr + m * 16 + fq * 4 + r;
      if (gm < M) {
#pragma unroll
        for (int n = 0; n < 4; ++n) {
          int gn = n0 + wc + n * 16 + fr;
          ps[(size_t)gm * N + gn] = acc[m][n][r];
        }
      }
    }
  }
}

// ------------------------------------------------------------------ 256x256-tile gate|up GEMM, 8 waves, 3-buffer counted-vmcnt,
// fused silu(gate)*up epilogue. Bt interleaved: 64-row groups, first 32 =
// gate cols [g*32,+32), last 32 = up of same cols. Wave n-frags 0,1 = gate,
// 2,3 = up -> in-register silu. Output [M][4096] bf16.
__global__ __launch_bounds__(512, 2) void gemm256gu(const bf16_t* __restrict__ A,
    const bf16_t* __restrict__ Bt, bf16_t* __restrict__ outb,
    int M, int K, int lda) {
  __shared__ __align__(16) bf16_t As[3][8192];
  __shared__ __align__(16) bf16_t Bs[3][8192];
  const int tid = threadIdx.x;
  const int lane = tid & 63, w = tid >> 6;
  const int m0 = blockIdx.y * 256, n0 = blockIdx.x * 256;
  const int wr = (w >> 2) * 128, wc = (w & 3) * 64;
  const int fq = lane >> 4, fr = lane & 15;
  const int f0 = tid, f1 = 512 + tid;
  const int r0 = f0 & 255, c0 = f0 >> 8;
  const int r1 = f1 & 255, c1 = f1 >> 8;
  const bf16_t* a0 = A + (size_t)(m0 + r0) * lda + c0 * 8;
  const bf16_t* a1 = A + (size_t)(m0 + r1) * lda + c1 * 8;
  const bf16_t* b0 = Bt + (size_t)(n0 + r0) * K + c0 * 8;
  const bf16_t* b1 = Bt + (size_t)(n0 + r1) * K + c1 * 8;
  const int l0 = (w * 64) * 8;
  const int l1 = (512 + w * 64) * 8;
  f32x4 zero = {0.f, 0.f, 0.f, 0.f};
  f32x4 acc[8][4];
#pragma unroll
  for (int m = 0; m < 8; ++m)
#pragma unroll
    for (int n = 0; n < 4; ++n) acc[m][n] = zero;
  const int nt = K >> 5;
  glds16(a0, &As[0][l0]); glds16(a1, &As[0][l1]);
  glds16(b0, &Bs[0][l0]); glds16(b1, &Bs[0][l1]);
  a0 += 32; a1 += 32; b0 += 32; b1 += 32;
  glds16(a0, &As[1][l0]); glds16(a1, &As[1][l1]);
  glds16(b0, &Bs[1][l0]); glds16(b1, &Bs[1][l1]);
  a0 += 32; a1 += 32; b0 += 32; b1 += 32;
  asm volatile("s_waitcnt vmcnt(4)" ::: "memory");
  __builtin_amdgcn_s_barrier();
  int cur = 0;
  for (int t = 0; t < nt; ++t) {
    int stg = cur + 2; if (stg >= 3) stg -= 3;
    if (t + 2 < nt) {
      glds16(a0, &As[stg][l0]); glds16(a1, &As[stg][l1]);
      glds16(b0, &Bs[stg][l0]); glds16(b1, &Bs[stg][l1]);
      a0 += 32; a1 += 32; b0 += 32; b1 += 32;
    }
    FragU bw[4];
#pragma unroll
    for (int n = 0; n < 4; ++n)
      bw[n].u = *(const uint4*)&Bs[cur][(fq * 256 + wc + n * 16 + fr) * 8];
    __builtin_amdgcn_s_setprio(1);
#pragma unroll
    for (int m = 0; m < 8; ++m) {
      FragU af;
      af.u = *(const uint4*)&As[cur][(fq * 256 + wr + m * 16 + fr) * 8];
#pragma unroll
      for (int n = 0; n < 4; ++n)
        acc[m][n] = MFMA_BF16(af.b, bw[n].b, acc[m][n]);
    }
    __builtin_amdgcn_s_setprio(0);
    if (t + 2 < nt) asm volatile("s_waitcnt vmcnt(4)" ::: "memory");
    else            asm volatile("s_waitcnt vmcnt(0)" ::: "memory");
    __builtin_amdgcn_s_barrier();
    cur = cur + 1; if (cur == 3) cur = 0;
  }
  // epilogue: j base for this wave = (n0 + wc)/2; n=0,1 gate, n=2,3 up
  const int jb = (n0 + wc) >> 1;
#pragma unroll
  for (int m = 0; m < 8; ++m) {
#pragma unroll
    for (int r = 0; r < 4; ++r) {
      int gm = m0 + wr + m * 16 + fq * 4 + r;
      if (gm < M) {
#pragma unroll
        for (int n = 0; n < 2; ++n) {
          int j = jb + n * 16 + fr;
          float g = acc[m][n][r];
          float u = acc[m][n + 2][r];
          float s = g / (1.f + __expf(-g));
          outb[(size_t)gm * 4096 + j] = (bf16_t)(s * u);
        }
      }
    }
  }
}

// ------------------------------------------------------------------ launch
extern "C" void kernel_launch(void* const* d_in, const int* in_sizes, int n_in,
                              void* d_out, int out_size, void* d_ws, size_t ws_size,
                              hipStream_t stream) {
  (void)in_sizes; (void)n_in; (void)out_size;
  const float* pixel     = (const float*)d_in[0];
  const int*   pos_ids   = (const int*)d_in[1];
  const float* w_patch   = (const float*)d_in[3];
  const float* qkv_w     = (const float*)d_in[4];
  const float* qkv_b     = (const float*)d_in[5];
  const float* q_norm_w  = (const float*)d_in[6];
  const float* k_norm_w  = (const float*)d_in[7];
  const float* proj_w    = (const float*)d_in[8];
  const float* proj_b    = (const float*)d_in[9];
  const float* norm1_w   = (const float*)d_in[10];
  const float* norm2_w   = (const float*)d_in[11];
  const float* gate_w    = (const float*)d_in[12];
  const float* up_w      = (const float*)d_in[13];
  const float* down_w    = (const float*)d_in[14];
  const float* post_ln_w = (const float*)d_in[15];
  const float* conv_w    = (const float*)d_in[16];
  const float* conv_b    = (const float*)d_in[17];
  const float* fc1_w     = (const float*)d_in[18];
  const float* fc1_b     = (const float*)d_in[19];
  const float* fc2_w     = (const float*)d_in[20];
  const float* fc2_b     = (const float*)d_in[21];
  float* out = (float*)d_out;

  char* wsb = (char*)d_ws;
  float*  h     = (float*)(wsb + 0);            // 9,830,400 B
  bf16_t* xo    = (bf16_t*)(wsb + 9830400);     // 4,915,200 B (x / o shared)
  char*   R1    = wsb + 14745600;               // 29,491,200 B multi-use
  bf16_t* qkvb  = (bf16_t*)(R1);
  bf16_t* qb    = (bf16_t*)(R1 + 14745600);
  bf16_t* kb    = (bf16_t*)(R1 + 19660800);
  bf16_t* vb    = (bf16_t*)(R1 + 24576000);
  bf16_t* gub   = (bf16_t*)(R1);                // 13,107,200 B activated gate*up
  bf16_t* pixb  = (bf16_t*)(R1);
  bf16_t* ab    = (bf16_t*)(R1);
  bf16_t* dbuf  = (bf16_t*)(R1 + 4915200);
  bf16_t* ebuf  = (bf16_t*)(R1 + 6144000);
  float*  skp   = (float*)(R1 + 11059200);      // 9,830,400 B split-K partials (head)
  float*  cosb  = (float*)(wsb + 44236800);     // 819,200 B
  float*  sinb  = (float*)(wsb + 45056000);     // 819,200 B
  char*   W     = wsb + 45875200;               // 56,623,104 B (per-layer bf16 weights)
  bf16_t* qkvwT = (bf16_t*)(W);
  bf16_t* projT = (bf16_t*)(W + 14155776);
  bf16_t* gateupT = (bf16_t*)(W + 18874368);    // (8192,1536) interleaved gate|up
  bf16_t* downT = (bf16_t*)(W + 44040192);
  bf16_t* convB = (bf16_t*)(W);
  bf16_t* fc1T  = (bf16_t*)(W + 18874368);
  bf16_t* fc2T  = (bf16_t*)(W + 37748736);
  bf16_t* wpT   = (bf16_t*)(wsb + 102498304);   // 3,637,248 B, ends 106,135,552
  float*  skp2  = (float*)(wsb + 106135552);    // 19,660,800 B split-K(2) partials
  const bool big_ws = ws_size >= (size_t)106135552 + 19660800;

  rope_k<<<1600, 64, 0, stream>>>(pos_ids, cosb, sinb);
  convert_pad_k<<<(1600 * 1184 + 255) / 256, 256, 0, stream>>>(pixel, pixb, 1600, 1176, 1184);
  transpose_cvt_v2<<<dim3(19, 24), 256, 0, stream>>>(w_patch, wpT, 1176, 1536, 1184);
  gemm64<0, 0, 0, 0><<<dim3(24, 25), 256, 0, stream>>>(
      pixb, wpT, nullptr, nullptr, h, nullptr, 1600, 1536, 1184, 1184);

  for (int l = 0; l < 4; ++l) {
    const float* qw = qkv_w  + (size_t)l * 1536 * 4608;
    const float* pw = proj_w + (size_t)l * 1536 * 1536;
    const float* gw = gate_w + (size_t)l * 1536 * 4096;
    const float* uw = up_w   + (size_t)l * 1536 * 4096;
    const float* dw = down_w + (size_t)l * 4096 * 1536;
    transpose_cvt_v2<<<dim3(24, 72), 256, 0, stream>>>(qw, qkvwT, 1536, 4608, 1536);
    transpose_cvt_v2<<<dim3(24, 24), 256, 0, stream>>>(pw, projT, 1536, 1536, 1536);
    transpose_cvt_gu_v2<<<dim3(24, 64), 256, 0, stream>>>(gw, gateupT, 1536, 4096, 1536, 0);
    transpose_cvt_gu_v2<<<dim3(24, 64), 256, 0, stream>>>(uw, gateupT, 1536, 4096, 1536, 32);
    transpose_cvt_v2<<<dim3(64, 24), 256, 0, stream>>>(dw, downT, 4096, 1536, 4096);

    rmsnorm_bf_k<<<1600, 256, 0, stream>>>(h, norm1_w + (size_t)l * 1536, xo, 1536);
    gemm128<0, 1, 0, 1><<<dim3(36, 13), 256, 0, stream>>>(
        xo, qkvwT, qkv_b + (size_t)l * 4608, nullptr, nullptr, qkvb, 1600, 4608, 1536, 1536);
    qknorm_rope_k<<<1600 * 12, 128, 0, stream>>>(
        qkvb, q_norm_w + (size_t)l * 128, k_norm_w + (size_t)l * 128, cosb, sinb, qb, kb);
    vtrans_k<<<dim3(12, 13), 256, 0, stream>>>(qkvb, vb);
    attn_mfma<<<300, 256, 0, stream>>>(qb, kb, vb, xo);
    if (big_ws) {
      gemm128sk<2><<<dim3(12, 13, 2), 256, 0, stream>>>(
          xo, projT, skp2, 1600, 1536, 1536, 1536);
      reduce2_res<1><<<(1600 * 1536 + 255) / 256, 256, 0, stream>>>(
          skp2, proj_b + (size_t)l * 1536, h, 1600, 1536);
    } else {
      gemm64<0, 1, 1, 0><<<dim3(24, 25), 256, 0, stream>>>(
          xo, projT, proj_b + (size_t)l * 1536, h, h, nullptr, 1600, 1536, 1536, 1536);
    }
    rmsnorm_bf_k<<<1600, 256, 0, stream>>>(h, norm2_w + (size_t)l * 1536, xo, 1536);
    gemm256gu<<<dim3(32, 7), 512, 0, stream>>>(
        xo, gateupT, gub, 1600, 1536, 1536);
    if (big_ws) {
      gemm128sk<2><<<dim3(12, 13, 2), 256, 0, stream>>>(
          gub, downT, skp2, 1600, 1536, 4096, 4096);
      reduce2_res<0><<<(1600 * 1536 + 255) / 256, 256, 0, stream>>>(
          skp2, nullptr, h, 1600, 1536);
    } else {
      gemm64<0, 0, 1, 0><<<dim3(24, 25), 256, 0, stream>>>(
          gub, downT, nullptr, h, h, nullptr, 1600, 1536, 4096, 4096);
    }
  }

  // head
  convert8_k<<<(1536 * 6144 / 8 + 255) / 256, 256, 0, stream>>>(conv_w, convB, 1536 * 6144 / 8);
  transpose_cvt_v2<<<dim3(24, 96), 256, 0, stream>>>(fc1_w, fc1T, 1536, 6144, 1536);
  transpose_cvt_v2<<<dim3(96, 24), 256, 0, stream>>>(fc2_w, fc2T, 6144, 1536, 6144);
  rmsnorm_bf_k<<<1600, 256, 0, stream>>>(h, post_ln_w, xo, 1536);
  gather_conv_k<<<(400 * 6144 + 255) / 256, 256, 0, stream>>>(xo, ab);
  gemm64sk<4><<<dim3(24, 7, 4), 256, 0, stream>>>(ab, convB, skp, 400, 1536, 6144, 6144);
  reduce_sk<4, 0, 1><<<(400 * 1536 + 255) / 256, 256, 0, stream>>>(
      skp, conv_b, nullptr, dbuf, 400, 1536);
  gemm64<1, 1, 0, 1><<<dim3(96, 7), 256, 0, stream>>>(
      dbuf, fc1T, fc1_b, nullptr, nullptr, ebuf, 400, 6144, 1536, 1536);
  gemm64sk<4><<<dim3(24, 7, 4), 256, 0, stream>>>(ebuf, fc2T, skp, 400, 1536, 6144, 6144);
  reduce_sk<4, 0, 0><<<(400 * 1536 + 255) / 256, 256, 0, stream>>>(
      skp, fc2_b, out, nullptr, 400, 1536);
}

// Round 25
// 1820.335 us; speedup vs baseline: 1.1195x; 1.0248x over previous
//
#include <hip/hip_runtime.h>
#include <math.h>

typedef __bf16 bf16_t;
typedef float f32x4 __attribute__((ext_vector_type(4)));
typedef __bf16 bf16x8 __attribute__((ext_vector_type(8)));

union FragU { uint4 u; bf16x8 b; };

#define MFMA_BF16(a, b, c) __builtin_amdgcn_mfma_f32_16x16x32_bf16((a), (b), (c), 0, 0, 0)

__device__ __forceinline__ void glds16(const void* g, void* l) {
  __builtin_amdgcn_global_load_lds((const __attribute__((address_space(1))) void*)g,
                                   (__attribute__((address_space(3))) void*)l, 16, 0, 0);
}

// ------------------------------------------------------------------ rope tables (fp32)
__global__ void rope_k(const int* __restrict__ pos_ids, float* __restrict__ cosb,
                       float* __restrict__ sinb) {
  int s = blockIdx.x;
  int d = threadIdx.x;            // 0..63
  int pair = d >> 5, j = d & 31;
  float p = (float)pos_ids[s * 2 + pair];
  float inv = powf(10000.f, -(float)j / 32.f);
  float v = p * inv;
  float c = cosf(v), sn = sinf(v);
  cosb[s * 128 + d] = c;  cosb[s * 128 + d + 64] = c;
  sinb[s * 128 + d] = sn; sinb[s * 128 + d + 64] = sn;
}

// ------------------------------------------------------------------ rmsnorm fp32 -> bf16
__global__ __launch_bounds__(256) void rmsnorm_bf_k(const float* __restrict__ in,
                                                    const float* __restrict__ w,
                                                    bf16_t* __restrict__ out, int cols) {
  int row = blockIdx.x;
  const float* x = in + (size_t)row * cols;
  float ss = 0.f;
  for (int c = threadIdx.x; c < cols; c += 256) { float v = x[c]; ss = fmaf(v, v, ss); }
#pragma unroll
  for (int o = 32; o; o >>= 1) ss += __shfl_xor(ss, o);
  __shared__ float red[4];
  if ((threadIdx.x & 63) == 0) red[threadIdx.x >> 6] = ss;
  __syncthreads();
  float tot = red[0] + red[1] + red[2] + red[3];
  float rs = rsqrtf(tot / (float)cols + 1e-6f);
  bf16_t* y = out + (size_t)row * cols;
  for (int c = threadIdx.x; c < cols; c += 256) y[c] = (bf16_t)(x[c] * rs * w[c]);
}

// ------------------------------------------------------------------ fused: h += (part0+part1 [+bias]); xo = rmsnorm(h)*nw  (N=1536)
template <int BIAS>
__global__ __launch_bounds__(256) void fused_red2_rms(const float* __restrict__ part,
    const float* __restrict__ bias, float* __restrict__ hio,
    const float* __restrict__ nw, bf16_t* __restrict__ xout, int M) {
  const int row = blockIdx.x;
  const size_t base = (size_t)row * 1536;
  float hv[6];
  float ss = 0.f;
#pragma unroll
  for (int i = 0; i < 6; ++i) {
    int c = threadIdx.x + i * 256;
    float v = part[base + c] + part[(size_t)M * 1536 + base + c];
    if (BIAS) v += bias[c];
    float hn = hio[base + c] + v;
    hio[base + c] = hn;
    hv[i] = hn;
    ss = fmaf(hn, hn, ss);
  }
#pragma unroll
  for (int o = 32; o; o >>= 1) ss += __shfl_xor(ss, o);
  __shared__ float red[4];
  if ((threadIdx.x & 63) == 0) red[threadIdx.x >> 6] = ss;
  __syncthreads();
  float tot = red[0] + red[1] + red[2] + red[3];
  float rs = rsqrtf(tot / 1536.f + 1e-6f);
#pragma unroll
  for (int i = 0; i < 6; ++i) {
    int c = threadIdx.x + i * 256;
    xout[base + c] = (bf16_t)(hv[i] * rs * nw[c]);
  }
}

// ------------------------------------------------------------------ transpose+convert v2: 64x64 tile, float4 loads, bf16x8 stores.
// in (K,N) f32 -> out (N,Kpad) bf16, zero-pad k>=K. N%64==0, Kpad%8==0.
__global__ __launch_bounds__(256) void transpose_cvt_v2(const float* __restrict__ in,
                                                        bf16_t* __restrict__ out,
                                                        int K, int N, int Kpad) {
  __shared__ float t[64][65];
  const int k0 = blockIdx.x * 64, n0 = blockIdx.y * 64;
  const int tx = threadIdx.x & 15, ty = threadIdx.x >> 4;   // tx:n/4, ty:k row
#pragma unroll
  for (int i = 0; i < 4; ++i) {
    int k = k0 + ty + 16 * i;
    float4 v = {0.f, 0.f, 0.f, 0.f};
    if (k < K) v = *(const float4*)&in[(size_t)k * N + n0 + tx * 4];
    t[ty + 16 * i][tx * 4 + 0] = v.x;
    t[ty + 16 * i][tx * 4 + 1] = v.y;
    t[ty + 16 * i][tx * 4 + 2] = v.z;
    t[ty + 16 * i][tx * 4 + 3] = v.w;
  }
  __syncthreads();
  const int nn = threadIdx.x >> 3;        // 0..31
  const int kc = (threadIdx.x & 7) * 8;   // 0..56
  if (k0 + kc < Kpad) {
#pragma unroll
    for (int p = 0; p < 2; ++p) {
      int n = n0 + nn + p * 32;
      bf16_t tmp[8];
#pragma unroll
      for (int j = 0; j < 8; ++j) tmp[j] = (bf16_t)t[kc + j][nn + p * 32];
      *(uint4*)&out[(size_t)n * Kpad + k0 + kc] = *(uint4*)tmp;
    }
  }
}

// ------------------------------------------------------------------ transpose+convert v2 for interleaved gate|up weights:
// dst row = (n/32)*64 + grpoff + (n%32)  (grpoff 0 = gate, 32 = up)
__global__ __launch_bounds__(256) void transpose_cvt_gu_v2(const float* __restrict__ in,
                                                           bf16_t* __restrict__ out,
                                                           int K, int N, int Kpad, int grpoff) {
  __shared__ float t[64][65];
  const int k0 = blockIdx.x * 64, n0 = blockIdx.y * 64;
  const int tx = threadIdx.x & 15, ty = threadIdx.x >> 4;
#pragma unroll
  for (int i = 0; i < 4; ++i) {
    int k = k0 + ty + 16 * i;
    float4 v = {0.f, 0.f, 0.f, 0.f};
    if (k < K) v = *(const float4*)&in[(size_t)k * N + n0 + tx * 4];
    t[ty + 16 * i][tx * 4 + 0] = v.x;
    t[ty + 16 * i][tx * 4 + 1] = v.y;
    t[ty + 16 * i][tx * 4 + 2] = v.z;
    t[ty + 16 * i][tx * 4 + 3] = v.w;
  }
  __syncthreads();
  const int nn = threadIdx.x >> 3;
  const int kc = (threadIdx.x & 7) * 8;
  if (k0 + kc < Kpad) {
#pragma unroll
    for (int p = 0; p < 2; ++p) {
      int n = n0 + nn + p * 32;
      int row = ((n >> 5) << 6) + grpoff + (n & 31);
      bf16_t tmp[8];
#pragma unroll
      for (int j = 0; j < 8; ++j) tmp[j] = (bf16_t)t[kc + j][nn + p * 32];
      *(uint4*)&out[(size_t)row * Kpad + k0 + kc] = *(uint4*)tmp;
    }
  }
}

// ------------------------------------------------------------------ straight convert with K-pad: in (R,K) f32 -> out (R,Kpad) bf16
__global__ void convert_pad_k(const float* __restrict__ in, bf16_t* __restrict__ out,
                              int R, int K, int Kpad) {
  int idx = blockIdx.x * 256 + threadIdx.x;
  if (idx < R * Kpad) {
    int r = idx / Kpad, k = idx - r * Kpad;
    out[idx] = (k < K) ? (bf16_t)in[(size_t)r * K + k] : (bf16_t)0.f;
  }
}

// ------------------------------------------------------------------ vectorized straight convert (no pad): 8 elems/thread
__global__ void convert8_k(const float* __restrict__ in, bf16_t* __restrict__ out, int n8) {
  int i = blockIdx.x * 256 + threadIdx.x;
  if (i < n8) {
    float4 a = ((const float4*)in)[2 * i];
    float4 b = ((const float4*)in)[2 * i + 1];
    bf16_t tmp[8] = {(bf16_t)a.x, (bf16_t)a.y, (bf16_t)a.z, (bf16_t)a.w,
                     (bf16_t)b.x, (bf16_t)b.y, (bf16_t)b.z, (bf16_t)b.w};
    ((uint4*)out)[i] = *(uint4*)tmp;
  }
}

// ------------------------------------------------------------------ qk rmsnorm + rope: qkv bf16 -> q_bf (scaled, [h][s][d]), k_bf
__global__ __launch_bounds__(128) void qknorm_rope_k(const bf16_t* __restrict__ qkv,
    const float* __restrict__ qn, const float* __restrict__ kn,
    const float* __restrict__ cosb, const float* __restrict__ sinb,
    bf16_t* __restrict__ qo, bf16_t* __restrict__ ko) {
  const int s = blockIdx.x / 12, h = blockIdx.x % 12;
  const int d = threadIdx.x;  // 0..127
  __shared__ float nrm[128];
  __shared__ float red[2];
  const float cs = cosb[s * 128 + d], sn = sinb[s * 128 + d];
  const float QS = 0.08838834764831845f * 1.4426950408889634f;  // D^-0.5 * log2(e)
#pragma unroll
  for (int part = 0; part < 2; ++part) {
    const bf16_t* p = qkv + (size_t)s * 4608 + part * 1536 + h * 128;
    float v = (float)p[d];
    float ss = v * v;
#pragma unroll
    for (int o = 32; o; o >>= 1) ss += __shfl_xor(ss, o);
    if ((d & 63) == 0) red[d >> 6] = ss;
    __syncthreads();
    float rs = rsqrtf((red[0] + red[1]) * (1.f / 128.f) + 1e-6f);
    float nv = v * rs * (part ? kn[d] : qn[d]);
    nrm[d] = nv;
    __syncthreads();
    float rot = (d < 64) ? -nrm[d + 64] : nrm[d - 64];
    float val = nv * cs + rot * sn;
    bf16_t* dst = part ? ko : qo;
    dst[((size_t)h * 1600 + s) * 128 + d] = (bf16_t)(part ? val : val * QS);
    __syncthreads();
  }
}

// ------------------------------------------------------------------ v transpose: qkv bf16 [s][2C + h*128 + d] -> vt [h][d][s]
__global__ __launch_bounds__(256) void vtrans_k(const bf16_t* __restrict__ qkv,
                                                bf16_t* __restrict__ vt) {
  __shared__ __align__(16) bf16_t t[128][136];
  const int h = blockIdx.x, s0 = blockIdx.y * 128;
  const int tx = threadIdx.x & 15, ty = threadIdx.x >> 4;
#pragma unroll
  for (int i = 0; i < 8; ++i) {
    int sl = ty + 16 * i, s = s0 + sl;
    uint4 v = {0u, 0u, 0u, 0u};
    if (s < 1600) v = *(const uint4*)&qkv[(size_t)s * 4608 + 3072 + h * 128 + tx * 8];
    *(uint4*)&t[sl][tx * 8] = v;
  }
  __syncthreads();
  if (s0 + tx * 8 < 1600) {
#pragma unroll
    for (int i = 0; i < 8; ++i) {
      int dd = ty + 16 * i;
      bf16_t tmp[8];
#pragma unroll
      for (int j = 0; j < 8; ++j) tmp[j] = t[tx * 8 + j][dd];
      *(uint4*)&vt[(size_t)(h * 128 + dd) * 1600 + s0 + tx * 8] = *(uint4*)tmp;
    }
  }
}

// ------------------------------------------------------------------ flash attention, LDS-staged K/V shared by 4 waves (64 q-rows/block),
// 3-buffer counted-vmcnt pipeline. Fixed-max softmax:
// score*log2e <= sqrt(128)*log2e = 16.33 -> p = exp2(s-16), no running max.
__global__ __launch_bounds__(256) void attn_mfma(const bf16_t* __restrict__ qg,
    const bf16_t* __restrict__ kg, const bf16_t* __restrict__ vg,
    bf16_t* __restrict__ o) {
  const int bid = blockIdx.x;                 // grid 300 = 12h * 25 qtiles
  const int xcd = bid & 7, sub = bid >> 3;
  const int swz = (xcd < 4 ? xcd * 38 : 4 * 38 + (xcd - 4) * 37) + sub;
  const int h = swz / 25;
  const int q0 = (swz % 25) * 64;
  const int tid = threadIdx.x;       // 0..255
  const int w = tid >> 6, lane = tid & 63;
  const int fq = lane >> 4, fr = lane & 15;
  const bf16_t* qh = qg + (size_t)h * 1600 * 128;
  const bf16_t* kh = kg + (size_t)h * 1600 * 128;
  const bf16_t* vh = vg + (size_t)h * 128 * 1600;
  __shared__ __align__(16) bf16_t Ks[3][4096];   // [cb16][key32][8]
  __shared__ __align__(16) bf16_t Vs[3][4096];   // [cb4][d128][8]
  __shared__ __align__(16) bf16_t pl[4][512];    // per-wave P [cb4][q16][8]
  int off_k[2], off_v[2], ldsb[2];
#pragma unroll
  for (int c = 0; c < 2; ++c) {
    int j = c * 256 + tid;
    off_k[c] = (j & 31) * 128 + (j >> 5) * 8;
    off_v[c] = (j & 127) * 1600 + (j >> 7) * 8;
    ldsb[c] = (c * 256 + w * 64) * 8;
  }
  FragU aq[4];
#pragma unroll
  for (int db = 0; db < 4; ++db)
    aq[db].u = *(const uint4*)&qh[(size_t)(q0 + w * 16 + fr) * 128 + db * 32 + fq * 8];
  f32x4 zero = {0.f, 0.f, 0.f, 0.f};
  f32x4 oacc[8];
#pragma unroll
  for (int nb = 0; nb < 8; ++nb) oacc[nb] = zero;
  float lrun[4] = {0.f, 0.f, 0.f, 0.f};
#pragma unroll
  for (int c = 0; c < 2; ++c) {
    glds16(kh + off_k[c], &Ks[0][ldsb[c]]);
    glds16(vh + off_v[c], &Vs[0][ldsb[c]]);
  }
#pragma unroll
  for (int c = 0; c < 2; ++c) {
    glds16(kh + 32 * 128 + off_k[c], &Ks[1][ldsb[c]]);
    glds16(vh + 32 + off_v[c], &Vs[1][ldsb[c]]);
  }
  asm volatile("s_waitcnt vmcnt(4)" ::: "memory");
  __builtin_amdgcn_s_barrier();
  int cur = 0;
  for (int t = 0; t < 50; ++t) {
    int stg = cur + 2; if (stg >= 3) stg -= 3;
    if (t + 2 < 50) {
      const int kb = (t + 2) * 32;
#pragma unroll
      for (int c = 0; c < 2; ++c) {
        glds16(kh + (size_t)kb * 128 + off_k[c], &Ks[stg][ldsb[c]]);
        glds16(vh + kb + off_v[c], &Vs[stg][ldsb[c]]);
      }
    }
    f32x4 s0 = zero, s1 = zero;
#pragma unroll
    for (int db = 0; db < 4; ++db) {
      FragU bk0, bk1;
      bk0.u = *(const uint4*)&Ks[cur][((db * 4 + fq) * 32 + fr) * 8];
      bk1.u = *(const uint4*)&Ks[cur][((db * 4 + fq) * 32 + 16 + fr) * 8];
      s0 = MFMA_BF16(aq[db].b, bk0.b, s0);
      s1 = MFMA_BF16(aq[db].b, bk1.b, s1);
    }
    float p0[4], p1[4];
#pragma unroll
    for (int r = 0; r < 4; ++r) {
      p0[r] = exp2f(s0[r] - 16.f);
      p1[r] = exp2f(s1[r] - 16.f);
      lrun[r] += p0[r] + p1[r];
    }
#pragma unroll
    for (int r = 0; r < 4; ++r) {
      int q = fq * 4 + r;
      int kk0 = fr;
      pl[w][((kk0 >> 3) * 16 + q) * 8 + (kk0 & 7)] = (bf16_t)p0[r];
      int kk1 = 16 + fr;
      pl[w][((kk1 >> 3) * 16 + q) * 8 + (kk1 & 7)] = (bf16_t)p1[r];
    }
    FragU ap;
    ap.u = *(const uint4*)&pl[w][(fq * 16 + fr) * 8];
#pragma unroll
    for (int nb = 0; nb < 8; ++nb) {
      FragU bv;
      bv.u = *(const uint4*)&Vs[cur][(fq * 128 + nb * 16 + fr) * 8];
      oacc[nb] = MFMA_BF16(ap.b, bv.b, oacc[nb]);
    }
    if (t + 2 < 50) asm volatile("s_waitcnt vmcnt(4)" ::: "memory");
    else            asm volatile("s_waitcnt vmcnt(0)" ::: "memory");
    __builtin_amdgcn_s_barrier();
    cur = cur + 1; if (cur == 3) cur = 0;
  }
#pragma unroll
  for (int r = 0; r < 4; ++r) {
    lrun[r] += __shfl_xor(lrun[r], 1);
    lrun[r] += __shfl_xor(lrun[r], 2);
    lrun[r] += __shfl_xor(lrun[r], 4);
    lrun[r] += __shfl_xor(lrun[r], 8);
  }
  float inv_[4];
#pragma unroll
  for (int r = 0; r < 4; ++r) inv_[r] = 1.f / lrun[r];
#pragma unroll
  for (int nb = 0; nb < 8; ++nb)
#pragma unroll
    for (int r = 0; r < 4; ++r) {
      int qq = q0 + w * 16 + fq * 4 + r;
      o[(size_t)qq * 1536 + h * 128 + nb * 16 + fr] = (bf16_t)(oacc[nb][r] * inv_[r]);
    }
}

// ------------------------------------------------------------------ gather for conv-as-GEMM (bf16)
__global__ void gather_conv_k(const bf16_t* __restrict__ hf, bf16_t* __restrict__ abuf) {
  int idx = blockIdx.x * 256 + threadIdx.x;  // 400*6144
  if (idx < 400 * 6144) {
    int n = idx / 6144, k = idx - n * 6144;
    abuf[idx] = hf[(size_t)(4 * n + (k & 3)) * 1536 + (k >> 2)];
  }
}

// ------------------------------------------------------------------ 64x64-tile bf16 MFMA GEMM, 3-buffer counted-vmcnt pipeline
template <int ACT, int BIAS, int RES, int OBF>
__global__ __launch_bounds__(256) void gemm64(const bf16_t* __restrict__ A,
    const bf16_t* __restrict__ Bt, const float* __restrict__ bias,
    const float* __restrict__ res, float* __restrict__ outf,
    bf16_t* __restrict__ outb, int M, int N, int K, int lda) {
  __shared__ __align__(16) bf16_t As[3][2048];  // [buf][cb4][row64][8]
  __shared__ __align__(16) bf16_t Bs[3][2048];
  const int tid = threadIdx.x;
  const int lane = tid & 63, w = tid >> 6;
  const int m0 = blockIdx.y * 64, n0 = blockIdx.x * 64;
  const int fq = lane >> 4, fr = lane & 15;
  const int wc = w * 16;
  const bf16_t* ag = A + (size_t)(m0 + lane) * lda + w * 8;
  const bf16_t* bg = Bt + (size_t)(n0 + lane) * K + w * 8;
  f32x4 zero = {0.f, 0.f, 0.f, 0.f};
  f32x4 acc[4];
#pragma unroll
  for (int m = 0; m < 4; ++m) acc[m] = zero;
  const int nt = K >> 5;
  glds16(ag, &As[0][w * 512]); glds16(bg, &Bs[0][w * 512]);
  ag += 32; bg += 32;
  glds16(ag, &As[1][w * 512]); glds16(bg, &Bs[1][w * 512]);
  ag += 32; bg += 32;
  asm volatile("s_waitcnt vmcnt(2)" ::: "memory");
  __builtin_amdgcn_s_barrier();
  int cur = 0;
  for (int t = 0; t < nt; ++t) {
    int stg = cur + 2; if (stg >= 3) stg -= 3;
    if (t + 2 < nt) {
      glds16(ag, &As[stg][w * 512]); glds16(bg, &Bs[stg][w * 512]);
      ag += 32; bg += 32;
    }
    FragU bw, af[4];
    bw.u = *(const uint4*)&Bs[cur][(fq * 64 + wc + fr) * 8];
#pragma unroll
    for (int m = 0; m < 4; ++m)
      af[m].u = *(const uint4*)&As[cur][(fq * 64 + m * 16 + fr) * 8];
#pragma unroll
    for (int m = 0; m < 4; ++m)
      acc[m] = MFMA_BF16(af[m].b, bw.b, acc[m]);
    if (t + 2 < nt) asm volatile("s_waitcnt vmcnt(2)" ::: "memory");
    else            asm volatile("s_waitcnt vmcnt(0)" ::: "memory");
    __builtin_amdgcn_s_barrier();
    cur = cur + 1; if (cur == 3) cur = 0;
  }
#pragma unroll
  for (int m = 0; m < 4; ++m) {
#pragma unroll
    for (int r = 0; r < 4; ++r) {
      int gm = m0 + m * 16 + fq * 4 + r;
      if (gm < M) {
        int gn = n0 + wc + fr;
        float v = acc[m][r];
        if (BIAS) v += bias[gn];
        if (ACT == 1) {
          float x = v;
          float t = 0.7978845608028654f * fmaf(0.044715f * x, x * x, x);
          float e = exp2f(t * 2.8853900817779268f);   // exp(2t)
          v = x * e / (e + 1.f);                       // 0.5x(1+tanh t)
        }
        if (RES) v += res[(size_t)gm * N + gn];
        if (OBF) outb[(size_t)gm * N + gn] = (bf16_t)v;
        else outf[(size_t)gm * N + gn] = v;
      }
    }
  }
}

// ------------------------------------------------------------------ 64x64-tile split-K GEMM: blockIdx.z covers K-chunk; fp32 partials.
template <int KS>
__global__ __launch_bounds__(256) void gemm64sk(const bf16_t* __restrict__ A,
    const bf16_t* __restrict__ Bt, float* __restrict__ part,
    int M, int N, int K, int lda) {
  __shared__ __align__(16) bf16_t As[3][2048];
  __shared__ __align__(16) bf16_t Bs[3][2048];
  const int tid = threadIdx.x;
  const int lane = tid & 63, w = tid >> 6;
  const int m0 = blockIdx.y * 64, n0 = blockIdx.x * 64;
  const int fq = lane >> 4, fr = lane & 15;
  const int wc = w * 16;
  const int kchunk = K / KS;
  const int kbase = blockIdx.z * kchunk;
  const bf16_t* ag = A + (size_t)(m0 + lane) * lda + kbase + w * 8;
  const bf16_t* bg = Bt + (size_t)(n0 + lane) * K + kbase + w * 8;
  f32x4 zero = {0.f, 0.f, 0.f, 0.f};
  f32x4 acc[4];
#pragma unroll
  for (int m = 0; m < 4; ++m) acc[m] = zero;
  const int nt = kchunk >> 5;
  glds16(ag, &As[0][w * 512]); glds16(bg, &Bs[0][w * 512]);
  ag += 32; bg += 32;
  glds16(ag, &As[1][w * 512]); glds16(bg, &Bs[1][w * 512]);
  ag += 32; bg += 32;
  asm volatile("s_waitcnt vmcnt(2)" ::: "memory");
  __builtin_amdgcn_s_barrier();
  int cur = 0;
  for (int t = 0; t < nt; ++t) {
    int stg = cur + 2; if (stg >= 3) stg -= 3;
    if (t + 2 < nt) {
      glds16(ag, &As[stg][w * 512]); glds16(bg, &Bs[stg][w * 512]);
      ag += 32; bg += 32;
    }
    FragU bw, af[4];
    bw.u = *(const uint4*)&Bs[cur][(fq * 64 + wc + fr) * 8];
#pragma unroll
    for (int m = 0; m < 4; ++m)
      af[m].u = *(const uint4*)&As[cur][(fq * 64 + m * 16 + fr) * 8];
#pragma unroll
    for (int m = 0; m < 4; ++m)
      acc[m] = MFMA_BF16(af[m].b, bw.b, acc[m]);
    if (t + 2 < nt) asm volatile("s_waitcnt vmcnt(2)" ::: "memory");
    else            asm volatile("s_waitcnt vmcnt(0)" ::: "memory");
    __builtin_amdgcn_s_barrier();
    cur = cur + 1; if (cur == 3) cur = 0;
  }
  float* ps = part + (size_t)blockIdx.z * M * N;
#pragma unroll
  for (int m = 0; m < 4; ++m) {
#pragma unroll
    for (int r = 0; r < 4; ++r) {
      int gm = m0 + m * 16 + fq * 4 + r;
      if (gm < M) {
        int gn = n0 + wc + fr;
        ps[(size_t)gm * N + gn] = acc[m][r];
      }
    }
  }
}

// ------------------------------------------------------------------ split-K reduce: sum KS slices + bias (+GELU), write bf16 or fp32
template <int KS, int ACT, int OBF>
__global__ void reduce_sk(const float* __restrict__ part, const float* __restrict__ bias,
                          float* __restrict__ outf, bf16_t* __restrict__ outb,
                          int M, int N) {
  int idx = blockIdx.x * 256 + threadIdx.x;
  if (idx < M * N) {
    int n = idx % N;
    float v = 0.f;
#pragma unroll
    for (int s = 0; s < KS; ++s) v += part[(size_t)s * M * N + idx];
    v += bias[n];
    if (ACT == 1) {
      float x = v;
      float t = 0.7978845608028654f * fmaf(0.044715f * x, x * x, x);
      float e = exp2f(t * 2.8853900817779268f);
      v = x * e / (e + 1.f);
    }
    if (OBF) outb[idx] = (bf16_t)v;
    else outf[idx] = v;
  }
}

// ------------------------------------------------------------------ split-K(2) reduce with residual accumulate into h (+optional bias)
template <int BIAS>
__global__ void reduce2_res(const float* __restrict__ part, const float* __restrict__ bias,
                            float* __restrict__ hio, int M, int N) {
  int idx = blockIdx.x * 256 + threadIdx.x;
  if (idx < M * N) {
    float v = part[idx] + part[(size_t)M * N + idx];
    if (BIAS) v += bias[idx % N];
    hio[idx] += v;
  }
}

// ------------------------------------------------------------------ 128x128-tile bf16 MFMA GEMM, 3-buffer counted-vmcnt pipeline (AI=64)
template <int ACT, int BIAS, int RES, int OBF>
__global__ __launch_bounds__(256) void gemm128(const bf16_t* __restrict__ A,
    const bf16_t* __restrict__ Bt, const float* __restrict__ bias,
    const float* __restrict__ res, float* __restrict__ outf,
    bf16_t* __restrict__ outb, int M, int N, int K, int lda) {
  __shared__ __align__(16) bf16_t As[3][4096];  // [buf][cb4][row128][8]
  __shared__ __align__(16) bf16_t Bs[3][4096];
  const int tid = threadIdx.x;
  const int lane = tid & 63, w = tid >> 6;
  const int m0 = blockIdx.y * 128, n0 = blockIdx.x * 128;
  const int wr = (w >> 1) * 64, wc = (w & 1) * 64;
  const int fq = lane >> 4, fr = lane & 15;
  const int u1 = w * 64 + lane, u2 = u1 + 256;
  const int r1 = u1 & 127, c1 = u1 >> 7;
  const int r2 = u2 & 127, c2 = u2 >> 7;
  const bf16_t* a1 = A + (size_t)(m0 + r1) * lda + c1 * 8;
  const bf16_t* a2 = A + (size_t)(m0 + r2) * lda + c2 * 8;
  const bf16_t* b1 = Bt + (size_t)(n0 + r1) * K + c1 * 8;
  const bf16_t* b2 = Bt + (size_t)(n0 + r2) * K + c2 * 8;
  f32x4 zero = {0.f, 0.f, 0.f, 0.f};
  f32x4 acc[4][4];
#pragma unroll
  for (int m = 0; m < 4; ++m)
#pragma unroll
    for (int n = 0; n < 4; ++n) acc[m][n] = zero;
  const int nt = K >> 5;
  glds16(a1, &As[0][w * 512]); glds16(a2, &As[0][2048 + w * 512]);
  glds16(b1, &Bs[0][w * 512]); glds16(b2, &Bs[0][2048 + w * 512]);
  a1 += 32; a2 += 32; b1 += 32; b2 += 32;
  glds16(a1, &As[1][w * 512]); glds16(a2, &As[1][2048 + w * 512]);
  glds16(b1, &Bs[1][w * 512]); glds16(b2, &Bs[1][2048 + w * 512]);
  a1 += 32; a2 += 32; b1 += 32; b2 += 32;
  asm volatile("s_waitcnt vmcnt(4)" ::: "memory");
  __builtin_amdgcn_s_barrier();
  int cur = 0;
  for (int t = 0; t < nt; ++t) {
    int stg = cur + 2; if (stg >= 3) stg -= 3;
    if (t + 2 < nt) {
      glds16(a1, &As[stg][w * 512]); glds16(a2, &As[stg][2048 + w * 512]);
      glds16(b1, &Bs[stg][w * 512]); glds16(b2, &Bs[stg][2048 + w * 512]);
      a1 += 32; a2 += 32; b1 += 32; b2 += 32;
    }
    FragU af[4], bw[4];
#pragma unroll
    for (int m = 0; m < 4; ++m)
      af[m].u = *(const uint4*)&As[cur][(fq * 128 + wr + m * 16 + fr) * 8];
#pragma unroll
    for (int n = 0; n < 4; ++n)
      bw[n].u = *(const uint4*)&Bs[cur][(fq * 128 + wc + n * 16 + fr) * 8];
#pragma unroll
    for (int m = 0; m < 4; ++m)
#pragma unroll
      for (int n = 0; n < 4; ++n)
        acc[m][n] = MFMA_BF16(af[m].b, bw[n].b, acc[m][n]);
    if (t + 2 < nt) asm volatile("s_waitcnt vmcnt(4)" ::: "memory");
    else            asm volatile("s_waitcnt vmcnt(0)" ::: "memory");
    __builtin_amdgcn_s_barrier();
    cur = cur + 1; if (cur == 3) cur = 0;
  }
#pragma unroll
  for (int m = 0; m < 4; ++m) {
#pragma unroll
    for (int r = 0; r < 4; ++r) {
      int gm = m0 + wr + m * 16 + fq * 4 + r;
      if (gm < M) {
#pragma unroll
        for (int n = 0; n < 4; ++n) {
          int gn = n0 + wc + n * 16 + fr;
          float v = acc[m][n][r];
          if (BIAS) v += bias[gn];
          if (ACT == 1) {
            float x = v;
            float t2 = 0.7978845608028654f * fmaf(0.044715f * x, x * x, x);
            float e = exp2f(t2 * 2.8853900817779268f);
            v = x * e / (e + 1.f);
          }
          if (RES) v += res[(size_t)gm * N + gn];
          if (OBF) outb[(size_t)gm * N + gn] = (bf16_t)v;
          else outf[(size_t)gm * N + gn] = v;
        }
      }
    }
  }
}

// ------------------------------------------------------------------ 128x128-tile split-K GEMM: blockIdx.z covers K-chunk; fp32 partials.
template <int KS>
__global__ __launch_bounds__(256) void gemm128sk(const bf16_t* __restrict__ A,
    const bf16_t* __restrict__ Bt, float* __restrict__ part,
    int M, int N, int K, int lda) {
  __shared__ __align__(16) bf16_t As[3][4096];
  __shared__ __align__(16) bf16_t Bs[3][4096];
  const int tid = threadIdx.x;
  const int lane = tid & 63, w = tid >> 6;
  const int m0 = blockIdx.y * 128, n0 = blockIdx.x * 128;
  const int wr = (w >> 1) * 64, wc = (w & 1) * 64;
  const int fq = lane >> 4, fr = lane & 15;
  const int u1 = w * 64 + lane, u2 = u1 + 256;
  const int r1 = u1 & 127, c1 = u1 >> 7;
  const int r2 = u2 & 127, c2 = u2 >> 7;
  const int kchunk = K / KS;
  const int kbase = blockIdx.z * kchunk;
  const bf16_t* a1 = A + (size_t)(m0 + r1) * lda + kbase + c1 * 8;
  const bf16_t* a2 = A + (size_t)(m0 + r2) * lda + kbase + c2 * 8;
  const bf16_t* b1 = Bt + (size_t)(n0 + r1) * K + kbase + c1 * 8;
  const bf16_t* b2 = Bt + (size_t)(n0 + r2) * K + kbase + c2 * 8;
  f32x4 zero = {0.f, 0.f, 0.f, 0.f};
  f32x4 acc[4][4];
#pragma unroll
  for (int m = 0; m < 4; ++m)
#pragma unroll
    for (int n = 0; n < 4; ++n) acc[m][n] = zero;
  const int nt = kchunk >> 5;
  glds16(a1, &As[0][w * 512]); glds16(a2, &As[0][2048 + w * 512]);
  glds16(b1, &Bs[0][w * 512]); glds16(b2, &Bs[0][2048 + w * 512]);
  a1 += 32; a2 += 32; b1 += 32; b2 += 32;
  glds16(a1, &As[1][w * 512]); glds16(a2, &As[1][2048 + w * 512]);
  glds16(b1, &Bs[1][w * 512]); glds16(b2, &Bs[1][2048 + w * 512]);
  a1 += 32; a2 += 32; b1 += 32; b2 += 32;
  asm volatile("s_waitcnt vmcnt(4)" ::: "memory");
  __builtin_amdgcn_s_barrier();
  int cur = 0;
  for (int t = 0; t < nt; ++t) {
    int stg = cur + 2; if (stg >= 3) stg -= 3;
    if (t + 2 < nt) {
      glds16(a1, &As[stg][w * 512]); glds16(a2, &As[stg][2048 + w * 512]);
      glds16(b1, &Bs[stg][w * 512]); glds16(b2, &Bs[stg][2048 + w * 512]);
      a1 += 32; a2 += 32; b1 += 32; b2 += 32;
    }
    FragU af[4], bw[4];
#pragma unroll
    for (int m = 0; m < 4; ++m)
      af[m].u = *(const uint4*)&As[cur][(fq * 128 + wr + m * 16 + fr) * 8];
#pragma unroll
    for (int n = 0; n < 4; ++n)
      bw[n].u = *(const uint4*)&Bs[cur][(fq * 128 + wc + n * 16 + fr) * 8];
#pragma unroll
    for (int m = 0; m < 4; ++m)
#pragma unroll
      for (int n = 0; n < 4; ++n)
        acc[m][n] = MFMA_BF16(af[m].b, bw[n].b, acc[m][n]);
    if (t + 2 < nt) asm volatile("s_waitcnt vmcnt(4)" ::: "memory");
    else            asm volatile("s_waitcnt vmcnt(0)" ::: "memory");
    __builtin_amdgcn_s_barrier();
    cur = cur + 1; if (cur == 3) cur = 0;
  }
  float* ps = part + (size_t)blockIdx.z * M * N;
#pragma unroll
  for (int m = 0; m < 4; ++m) {
#pragma unroll
    for (int r = 0; r < 4; ++r) {
      int gm = m0 + wr + m * 16 + fq * 4 + r;
      if (gm < M) {
#pragma unroll
        for (int n = 0; n < 4; ++n) {
          int gn = n0 + wc + n * 16 + fr;
          ps[(size_t)gm * N + gn] = acc[m][n][r];
        }
      }
    }
  }
}

// ------------------------------------------------------------------ 256x256-tile gate|up GEMM, 8 waves, 3-buffer counted-vmcnt,
// fused silu(gate)*up epilogue. Bt interleaved: 64-row groups, first 32 =
// gate cols [g*32,+32), last 32 = up of same cols. Wave n-frags 0,1 = gate,
// 2,3 = up -> in-register silu. Output [M][4096] bf16.
__global__ __launch_bounds__(512, 2) void gemm256gu(const bf16_t* __restrict__ A,
    const bf16_t* __restrict__ Bt, bf16_t* __restrict__ outb,
    int M, int K, int lda) {
  __shared__ __align__(16) bf16_t As[3][8192];
  __shared__ __align__(16) bf16_t Bs[3][8192];
  const int tid = threadIdx.x;
  const int lane = tid & 63, w = tid >> 6;
  const int m0 = blockIdx.y * 256, n0 = blockIdx.x * 256;
  const int wr = (w >> 2) * 128, wc = (w & 3) * 64;
  const int fq = lane >> 4, fr = lane & 15;
  const int f0 = tid, f1 = 512 + tid;
  const int r0 = f0 & 255, c0 = f0 >> 8;
  const int r1 = f1 & 255, c1 = f1 >> 8;
  const bf16_t* a0 = A + (size_t)(m0 + r0) * lda + c0 * 8;
  const bf16_t* a1 = A + (size_t)(m0 + r1) * lda + c1 * 8;
  const bf16_t* b0 = Bt + (size_t)(n0 + r0) * K + c0 * 8;
  const bf16_t* b1 = Bt + (size_t)(n0 + r1) * K + c1 * 8;
  const int l0 = (w * 64) * 8;
  const int l1 = (512 + w * 64) * 8;
  f32x4 zero = {0.f, 0.f, 0.f, 0.f};
  f32x4 acc[8][4];
#pragma unroll
  for (int m = 0; m < 8; ++m)
#pragma unroll
    for (int n = 0; n < 4; ++n) acc[m][n] = zero;
  const int nt = K >> 5;
  glds16(a0, &As[0][l0]); glds16(a1, &As[0][l1]);
  glds16(b0, &Bs[0][l0]); glds16(b1, &Bs[0][l1]);
  a0 += 32; a1 += 32; b0 += 32; b1 += 32;
  glds16(a0, &As[1][l0]); glds16(a1, &As[1][l1]);
  glds16(b0, &Bs[1][l0]); glds16(b1, &Bs[1][l1]);
  a0 += 32; a1 += 32; b0 += 32; b1 += 32;
  asm volatile("s_waitcnt vmcnt(4)" ::: "memory");
  __builtin_amdgcn_s_barrier();
  int cur = 0;
  for (int t = 0; t < nt; ++t) {
    int stg = cur + 2; if (stg >= 3) stg -= 3;
    if (t + 2 < nt) {
      glds16(a0, &As[stg][l0]); glds16(a1, &As[stg][l1]);
      glds16(b0, &Bs[stg][l0]); glds16(b1, &Bs[stg][l1]);
      a0 += 32; a1 += 32; b0 += 32; b1 += 32;
    }
    FragU bw[4];
#pragma unroll
    for (int n = 0; n < 4; ++n)
      bw[n].u = *(const uint4*)&Bs[cur][(fq * 256 + wc + n * 16 + fr) * 8];
    __builtin_amdgcn_s_setprio(1);
#pragma unroll
    for (int m = 0; m < 8; ++m) {
      FragU af;
      af.u = *(const uint4*)&As[cur][(fq * 256 + wr + m * 16 + fr) * 8];
#pragma unroll
      for (int n = 0; n < 4; ++n)
        acc[m][n] = MFMA_BF16(af.b, bw[n].b, acc[m][n]);
    }
    __builtin_amdgcn_s_setprio(0);
    if (t + 2 < nt) asm volatile("s_waitcnt vmcnt(4)" ::: "memory");
    else            asm volatile("s_waitcnt vmcnt(0)" ::: "memory");
    __builtin_amdgcn_s_barrier();
    cur = cur + 1; if (cur == 3) cur = 0;
  }
  // epilogue: j base for this wave = (n0 + wc)/2; n=0,1 gate, n=2,3 up
  const int jb = (n0 + wc) >> 1;
#pragma unroll
  for (int m = 0; m < 8; ++m) {
#pragma unroll
    for (int r = 0; r < 4; ++r) {
      int gm = m0 + wr + m * 16 + fq * 4 + r;
      if (gm < M) {
#pragma unroll
        for (int n = 0; n < 2; ++n) {
          int j = jb + n * 16 + fr;
          float g = acc[m][n][r];
          float u = acc[m][n + 2][r];
          float s = g / (1.f + __expf(-g));
          outb[(size_t)gm * 4096 + j] = (bf16_t)(s * u);
        }
      }
    }
  }
}

// ------------------------------------------------------------------ launch
extern "C" void kernel_launch(void* const* d_in, const int* in_sizes, int n_in,
                              void* d_out, int out_size, void* d_ws, size_t ws_size,
                              hipStream_t stream) {
  (void)in_sizes; (void)n_in; (void)out_size;
  const float* pixel     = (const float*)d_in[0];
  const int*   pos_ids   = (const int*)d_in[1];
  const float* w_patch   = (const float*)d_in[3];
  const float* qkv_w     = (const float*)d_in[4];
  const float* qkv_b     = (const float*)d_in[5];
  const float* q_norm_w  = (const float*)d_in[6];
  const float* k_norm_w  = (const float*)d_in[7];
  const float* proj_w    = (const float*)d_in[8];
  const float* proj_b    = (const float*)d_in[9];
  const float* norm1_w   = (const float*)d_in[10];
  const float* norm2_w   = (const float*)d_in[11];
  const float* gate_w    = (const float*)d_in[12];
  const float* up_w      = (const float*)d_in[13];
  const float* down_w    = (const float*)d_in[14];
  const float* post_ln_w = (const float*)d_in[15];
  const float* conv_w    = (const float*)d_in[16];
  const float* conv_b    = (const float*)d_in[17];
  const float* fc1_w     = (const float*)d_in[18];
  const float* fc1_b     = (const float*)d_in[19];
  const float* fc2_w     = (const float*)d_in[20];
  const float* fc2_b     = (const float*)d_in[21];
  float* out = (float*)d_out;

  char* wsb = (char*)d_ws;
  float*  h     = (float*)(wsb + 0);            // 9,830,400 B
  bf16_t* xo    = (bf16_t*)(wsb + 9830400);     // 4,915,200 B (x / o shared)
  char*   R1    = wsb + 14745600;               // 29,491,200 B multi-use
  bf16_t* qkvb  = (bf16_t*)(R1);
  bf16_t* qb    = (bf16_t*)(R1 + 14745600);
  bf16_t* kb    = (bf16_t*)(R1 + 19660800);
  bf16_t* vb    = (bf16_t*)(R1 + 24576000);
  bf16_t* gub   = (bf16_t*)(R1);                // 13,107,200 B activated gate*up
  bf16_t* pixb  = (bf16_t*)(R1);
  bf16_t* ab    = (bf16_t*)(R1);
  bf16_t* dbuf  = (bf16_t*)(R1 + 4915200);
  bf16_t* ebuf  = (bf16_t*)(R1 + 6144000);
  float*  skp   = (float*)(R1 + 11059200);      // 9,830,400 B split-K partials (head)
  float*  cosb  = (float*)(wsb + 44236800);     // 819,200 B
  float*  sinb  = (float*)(wsb + 45056000);     // 819,200 B
  char*   W     = wsb + 45875200;               // 56,623,104 B (per-layer bf16 weights)
  bf16_t* qkvwT = (bf16_t*)(W);
  bf16_t* projT = (bf16_t*)(W + 14155776);
  bf16_t* gateupT = (bf16_t*)(W + 18874368);    // (8192,1536) interleaved gate|up
  bf16_t* downT = (bf16_t*)(W + 44040192);
  bf16_t* convB = (bf16_t*)(W);
  bf16_t* fc1T  = (bf16_t*)(W + 18874368);
  bf16_t* fc2T  = (bf16_t*)(W + 37748736);
  bf16_t* wpT   = (bf16_t*)(wsb + 102498304);   // 3,637,248 B, ends 106,135,552
  float*  skp2  = (float*)(wsb + 106135552);    // 19,660,800 B split-K(2) partials
  const bool big_ws = ws_size >= (size_t)106135552 + 19660800;

  rope_k<<<1600, 64, 0, stream>>>(pos_ids, cosb, sinb);
  convert_pad_k<<<(1600 * 1184 + 255) / 256, 256, 0, stream>>>(pixel, pixb, 1600, 1176, 1184);
  transpose_cvt_v2<<<dim3(19, 24), 256, 0, stream>>>(w_patch, wpT, 1176, 1536, 1184);
  gemm64<0, 0, 0, 0><<<dim3(24, 25), 256, 0, stream>>>(
      pixb, wpT, nullptr, nullptr, h, nullptr, 1600, 1536, 1184, 1184);
  if (big_ws) {
    // layer-0 norm1 hoisted (subsequent norms are fused into reduces)
    rmsnorm_bf_k<<<1600, 256, 0, stream>>>(h, norm1_w, xo, 1536);
  }

  for (int l = 0; l < 4; ++l) {
    const float* qw = qkv_w  + (size_t)l * 1536 * 4608;
    const float* pw = proj_w + (size_t)l * 1536 * 1536;
    const float* gw = gate_w + (size_t)l * 1536 * 4096;
    const float* uw = up_w   + (size_t)l * 1536 * 4096;
    const float* dw = down_w + (size_t)l * 4096 * 1536;
    transpose_cvt_v2<<<dim3(24, 72), 256, 0, stream>>>(qw, qkvwT, 1536, 4608, 1536);
    transpose_cvt_v2<<<dim3(24, 24), 256, 0, stream>>>(pw, projT, 1536, 1536, 1536);
    transpose_cvt_gu_v2<<<dim3(24, 64), 256, 0, stream>>>(gw, gateupT, 1536, 4096, 1536, 0);
    transpose_cvt_gu_v2<<<dim3(24, 64), 256, 0, stream>>>(uw, gateupT, 1536, 4096, 1536, 32);
    transpose_cvt_v2<<<dim3(64, 24), 256, 0, stream>>>(dw, downT, 4096, 1536, 4096);

    if (!big_ws) {
      rmsnorm_bf_k<<<1600, 256, 0, stream>>>(h, norm1_w + (size_t)l * 1536, xo, 1536);
    }
    gemm128<0, 1, 0, 1><<<dim3(36, 13), 256, 0, stream>>>(
        xo, qkvwT, qkv_b + (size_t)l * 4608, nullptr, nullptr, qkvb, 1600, 4608, 1536, 1536);
    qknorm_rope_k<<<1600 * 12, 128, 0, stream>>>(
        qkvb, q_norm_w + (size_t)l * 128, k_norm_w + (size_t)l * 128, cosb, sinb, qb, kb);
    vtrans_k<<<dim3(12, 13), 256, 0, stream>>>(qkvb, vb);
    attn_mfma<<<300, 256, 0, stream>>>(qb, kb, vb, xo);
    if (big_ws) {
      gemm128sk<2><<<dim3(12, 13, 2), 256, 0, stream>>>(
          xo, projT, skp2, 1600, 1536, 1536, 1536);
      fused_red2_rms<1><<<1600, 256, 0, stream>>>(
          skp2, proj_b + (size_t)l * 1536, h, norm2_w + (size_t)l * 1536, xo, 1600);
    } else {
      gemm64<0, 1, 1, 0><<<dim3(24, 25), 256, 0, stream>>>(
          xo, projT, proj_b + (size_t)l * 1536, h, h, nullptr, 1600, 1536, 1536, 1536);
      rmsnorm_bf_k<<<1600, 256, 0, stream>>>(h, norm2_w + (size_t)l * 1536, xo, 1536);
    }
    gemm256gu<<<dim3(32, 7), 512, 0, stream>>>(
        xo, gateupT, gub, 1600, 1536, 1536);
    if (big_ws) {
      gemm128sk<2><<<dim3(12, 13, 2), 256, 0, stream>>>(
          gub, downT, skp2, 1600, 1536, 4096, 4096);
      const float* nw = (l < 3) ? (norm1_w + (size_t)(l + 1) * 1536) : post_ln_w;
      fused_red2_rms<0><<<1600, 256, 0, stream>>>(
          skp2, nullptr, h, nw, xo, 1600);
    } else {
      gemm64<0, 0, 1, 0><<<dim3(24, 25), 256, 0, stream>>>(
          gub, downT, nullptr, h, h, nullptr, 1600, 1536, 4096, 4096);
    }
  }

  // head (big_ws: xo already holds post_ln-normed h from the last fused reduce)
  convert8_k<<<(1536 * 6144 / 8 + 255) / 256, 256, 0, stream>>>(conv_w, convB, 1536 * 6144 / 8);
  transpose_cvt_v2<<<dim3(24, 96), 256, 0, stream>>>(fc1_w, fc1T, 1536, 6144, 1536);
  transpose_cvt_v2<<<dim3(96, 24), 256, 0, stream>>>(fc2_w, fc2T, 6144, 1536, 6144);
  if (!big_ws) {
    rmsnorm_bf_k<<<1600, 256, 0, stream>>>(h, post_ln_w, xo, 1536);
  }
  gather_conv_k<<<(400 * 6144 + 255) / 256, 256, 0, stream>>>(xo, ab);
  gemm64sk<4><<<dim3(24, 7, 4), 256, 0, stream>>>(ab, convB, skp, 400, 1536, 6144, 6144);
  reduce_sk<4, 0, 1><<<(400 * 1536 + 255) / 256, 256, 0, stream>>>(
      skp, conv_b, nullptr, dbuf, 400, 1536);
  gemm64<1, 1, 0, 1><<<dim3(96, 7), 256, 0, stream>>>(
      dbuf, fc1T, fc1_b, nullptr, nullptr, ebuf, 400, 6144, 1536, 1536);
  gemm64sk<4><<<dim3(24, 7, 4), 256, 0, stream>>>(ebuf, fc2T, skp, 400, 1536, 6144, 6144);
  reduce_sk<4, 0, 0><<<(400 * 1536 + 255) / 256, 256, 0, stream>>>(
      skp, fc2_b, out, nullptr, 400, 1536);
}